// Round 10
// baseline (741.804 us; speedup 1.0000x reference)
//
#include <hip/hip_runtime.h>
#include <hip/hip_fp16.h>
#include <math.h>

// RelationMessagePassing — bf16 MFMA, N-split waves, 128-row tiles,
// conflict-free linear-chunk gather, packed-fp16 atomic scatter.
//
// Round-9: N-split cut rel time 45% (weight traffic was binder). Remaining:
// ~95% of block time is non-MFMA overhead; 3.2M LDS bank conflicts from the
// 8-lanes-per-row gather writes. This round: 128-row tiles (half the blocks,
// half the weight traffic + barriers per tuple) and a gather where lane l
// writes LDS byte g*16 ^ ((r&7)<<4), g = linear chunk id (consecutive lanes
// cover whole rows -> zero write conflicts). Ids array dropped; epilogue
// re-reads idx from global (L1-hot).
//
// Pipeline: memset exps(fp16) | conv_states | transpose_w (W2 pre-scaled 8) |
//   rel_mfma<64/128/192> (128 tuples/block): gather->L1->bar->H->bar->L2 ->
//     blockmax store + pk_f16 atomic exp(acc') -> reduce_max |
//   up_mfma: max_msg = log(1e-16+S*e^-8M)/8+M; concat; MFMA; fp32 out.

typedef __attribute__((ext_vector_type(8))) short bf16x8;
typedef __attribute__((ext_vector_type(4))) float f32x4;
typedef __attribute__((ext_vector_type(8))) _Float16 f16x8;
typedef unsigned short u16;

__device__ __forceinline__ u16 f2bf(float f) {   // RNE f32->bf16 (finite)
    unsigned u = __float_as_uint(f);
    return (u16)((u + 0x7fffu + ((u >> 16) & 1u)) >> 16);
}

// ---------------- prep ----------------
__global__ __launch_bounds__(256) void conv_states(const float* __restrict__ src,
                                                   u16* __restrict__ dst, int n8) {
    int i = blockIdx.x * 256 + threadIdx.x;
    if (i >= n8) return;
    float4 a = reinterpret_cast<const float4*>(src)[2 * i];
    float4 b = reinterpret_cast<const float4*>(src)[2 * i + 1];
    bf16x8 v;
    v[0] = (short)f2bf(a.x); v[1] = (short)f2bf(a.y);
    v[2] = (short)f2bf(a.z); v[3] = (short)f2bf(a.w);
    v[4] = (short)f2bf(b.x); v[5] = (short)f2bf(b.y);
    v[6] = (short)f2bf(b.z); v[7] = (short)f2bf(b.w);
    reinterpret_cast<bf16x8*>(dst)[i] = v;
}

struct TEnt { const float* src; u16* dst; int K, N, base; float scale; };
struct TPack { TEnt e[8]; };
// dst[n*K + k] = bf16(scale * src[k*N + n])
__global__ __launch_bounds__(256) void transpose_w(TPack p) {
    int b = blockIdx.x;
    int i = 0;
    while (i < 7 && b >= p.e[i + 1].base) ++i;
    TEnt e = p.e[i];
    int idx = (b - e.base) * 256 + threadIdx.x;
    if (idx < e.K * e.N) {
        int n = idx / e.K, k = idx - n * e.K;
        e.dst[idx] = f2bf(e.scale * e.src[k * e.N + n]);
    }
}

// ---------------- relation kernels ----------------
// D = arity*64; block = 128 tuples, 4 waves; wave w owns cols
// [w*D/4,(w+1)*D/4) x all 128 rows. Layer2 pre-scaled by 8 => acc' = 8*o.
template <int D>
__global__ __launch_bounds__(256) void rel_mfma(
    const u16* __restrict__ statesb, const int* __restrict__ idx,
    const u16* __restrict__ W1t, const float* __restrict__ B1,
    const u16* __restrict__ W2t, const float* __restrict__ B2,
    __half* __restrict__ exps, float* __restrict__ blockmax, int E) {
    constexpr int A = D / 64;
    constexpr int KF = D / 32;
    constexpr int NFW = D / 64;          // N-frags per wave (D/4 cols)
    constexpr int CPR = D / 8;           // 16B chunks per LDS row
    constexpr int ISS = D / 16;          // gather issues per wave (32 rows/wave)
    __shared__ __align__(16) u16 Xs[128 * D];
    __shared__ float wmax[4];
    char* Xc = (char*)Xs;

    const int tid = threadIdx.x;
    const int block0 = blockIdx.x * 128;
    const int validRows = min(128, E - block0);
    const int validSegs = validRows * A;
    const long long segBase = (long long)block0 * A;

    const int l = tid & 63;
    const int w = tid >> 6;

    // ---- gather: lane l of issue i handles linear chunk g; conflict-free
    // LDS dest byte = g*16 ^ ((r&7)<<4); global chunk = (c&7)^(r&7) of node.
    {
        const int wchunk0 = w * 32 * CPR;
        #pragma unroll
        for (int i = 0; i < ISS; ++i) {
            int g = wchunk0 + i * 64 + l;
            int r = g / CPR;
            int c = g - r * CPR;
            int slot = c >> 3;
            int wc = (c & 7) ^ (r & 7);
            int seg = min(r * A + slot, validSegs - 1);
            int node = idx[segBase + seg];
            bf16x8 v = *reinterpret_cast<const bf16x8*>(
                statesb + (long long)node * 64 + wc * 8);
            *reinterpret_cast<bf16x8*>(Xc + ((g * 16) ^ ((r & 7) << 4))) = v;
        }
    }
    __syncthreads();

    const int ln = l & 15, kq = l >> 4;
    const int nbase = w * NFW;           // global N-frag base for this wave

    f32x4 acc[8][NFW];

    // ---- layer 1: h = relu(x@W1 + b1); wave: its col slice x 128 rows
    #pragma unroll
    for (int nf = 0; nf < NFW; ++nf) {
        float b = B1[(nbase + nf) * 16 + ln];
        #pragma unroll
        for (int m = 0; m < 8; ++m) acc[m][nf] = {b, b, b, b};
    }
    #pragma unroll
    for (int kf = 0; kf < KF; ++kf) {
        bf16x8 a[8];
        #pragma unroll
        for (int m = 0; m < 8; ++m)
            a[m] = *reinterpret_cast<const bf16x8*>(
                Xc + (m * 16 + ln) * (2 * D) + ((kf * 64 + kq * 16) ^ ((ln & 7) << 4)));
        #pragma unroll
        for (int nf = 0; nf < NFW; ++nf) {
            bf16x8 b = *reinterpret_cast<const bf16x8*>(
                W1t + ((nbase + nf) * 16 + ln) * D + kf * 32 + kq * 8);
            #pragma unroll
            for (int m = 0; m < 8; ++m)
                acc[m][nf] = __builtin_amdgcn_mfma_f32_16x16x32_bf16(a[m], b, acc[m][nf], 0, 0, 0);
        }
    }
    __syncthreads();   // all waves done reading X
    // relu -> H (this wave's col slice, all 128 rows)
    #pragma unroll
    for (int nf = 0; nf < NFW; ++nf) {
        const int c = (nbase + nf) * 16 + ln;
        #pragma unroll
        for (int m = 0; m < 8; ++m)
            #pragma unroll
            for (int j = 0; j < 4; ++j) {
                int row = m * 16 + kq * 4 + j;
                int byte = (c * 2) ^ ((row & 7) << 4);
                *reinterpret_cast<u16*>(Xc + row * (2 * D) + byte) =
                    f2bf(fmaxf(acc[m][nf][j], 0.f));
            }
    }
    __syncthreads();   // H complete

    // ---- layer 2 (pre-scaled): acc' = 8*(h@W2 + b2)
    #pragma unroll
    for (int nf = 0; nf < NFW; ++nf) {
        float b = 8.f * B2[(nbase + nf) * 16 + ln];
        #pragma unroll
        for (int m = 0; m < 8; ++m) acc[m][nf] = {b, b, b, b};
    }
    #pragma unroll
    for (int kf = 0; kf < KF; ++kf) {
        bf16x8 a[8];
        #pragma unroll
        for (int m = 0; m < 8; ++m)
            a[m] = *reinterpret_cast<const bf16x8*>(
                Xc + (m * 16 + ln) * (2 * D) + ((kf * 64 + kq * 16) ^ ((ln & 7) << 4)));
        #pragma unroll
        for (int nf = 0; nf < NFW; ++nf) {
            bf16x8 b = *reinterpret_cast<const bf16x8*>(
                W2t + ((nbase + nf) * 16 + ln) * D + kf * 32 + kq * 8);
            #pragma unroll
            for (int m = 0; m < 8; ++m)
                acc[m][nf] = __builtin_amdgcn_mfma_f32_16x16x32_bf16(a[m], b, acc[m][nf], 0, 0, 0);
        }
    }

    // ---- epilogue: block max (plain store) + packed fp16 exp scatter
    float m = -INFINITY;
    #pragma unroll
    for (int mf = 0; mf < 8; ++mf)
        #pragma unroll
        for (int nf = 0; nf < NFW; ++nf)
            #pragma unroll
            for (int j = 0; j < 4; ++j) {
                int row = mf * 16 + kq * 4 + j;
                if (row < validRows) m = fmaxf(m, acc[mf][nf][j]);
            }
    #pragma unroll
    for (int off = 32; off; off >>= 1) m = fmaxf(m, __shfl_xor(m, off));
    if (l == 0) wmax[w] = m;
    __syncthreads();
    if (tid == 0)
        blockmax[blockIdx.x] =
            0.125f * fmaxf(fmaxf(wmax[0], wmax[1]), fmaxf(wmax[2], wmax[3]));

    // even lanes issue one pk_add_f16 covering (feat, feat+1)
    #pragma unroll
    for (int nf = 0; nf < NFW; ++nf) {
        const int c = (nbase + nf) * 16 + ln;
        const int slot = c >> 6;
        const int feat = c & 63;
        #pragma unroll
        for (int mf = 0; mf < 8; ++mf)
            #pragma unroll
            for (int j = 0; j < 4; ++j) {
                int row = mf * 16 + kq * 4 + j;
                float v = __expf(acc[mf][nf][j]);
                float nv = __shfl_xor(v, 1);
                if ((ln & 1) == 0 && row < validRows) {
                    int node = idx[segBase + row * A + slot];
                    __half2 pk = __halves2half2(__float2half(v), __float2half(nv));
                    unsafeAtomicAdd(
                        reinterpret_cast<__half2*>(exps + (long long)node * 64 + feat), pk);
                }
            }
    }
}

// ---------------- global max over block maxima ----------------
__global__ __launch_bounds__(256) void reduce_max(const float* __restrict__ bm,
                                                  int n, float* __restrict__ out) {
    __shared__ float ws_[4];
    float m = -INFINITY;
    for (int i = threadIdx.x; i < n; i += 256) m = fmaxf(m, bm[i]);
    #pragma unroll
    for (int off = 32; off; off >>= 1) m = fmaxf(m, __shfl_xor(m, off));
    if ((threadIdx.x & 63) == 0) ws_[threadIdx.x >> 6] = m;
    __syncthreads();
    if (threadIdx.x == 0)
        out[0] = fmaxf(fmaxf(ws_[0], ws_[1]), fmaxf(ws_[2], ws_[3]));
}

// ---------------- up kernel ----------------
__global__ __launch_bounds__(256) void up_mfma(
    const u16* __restrict__ statesb, const _Float16* __restrict__ exps,
    const float* __restrict__ gmaxp,
    const u16* __restrict__ W1t, const float* __restrict__ B1,
    const u16* __restrict__ W2t, const float* __restrict__ B2,
    float* __restrict__ outp, int Nn) {
    constexpr int D = 128;
    __shared__ __align__(16) u16 Xs[64 * D];
    char* Xc = (char*)Xs;
    const int tid = threadIdx.x;
    const int block0 = blockIdx.x * 64;
    const int validRows = min(64, Nn - block0);
    const float M = gmaxp[0];
    const float EM = __expf(-8.f * M);

    // X tile: cols 0..63 = max_msg, 64..127 = states
    for (int q = tid; q < 64 * 16; q += 256) {
        int r = q >> 4, p = q & 15;
        bf16x8 v = {};
        if (r < validRows) {
            long long nd = block0 + r;
            if (p < 8) {
                f16x8 s = *reinterpret_cast<const f16x8*>(exps + nd * 64 + p * 8);
                #pragma unroll
                for (int i = 0; i < 8; ++i)
                    v[i] = (short)f2bf(__logf(1e-16f + (float)s[i] * EM) * 0.125f + M);
            } else {
                v = *reinterpret_cast<const bf16x8*>(statesb + nd * 64 + (p - 8) * 8);
            }
        }
        int byte = (p * 16) ^ ((r & 7) << 4);
        *reinterpret_cast<bf16x8*>(Xc + r * 256 + byte) = v;
    }
    __syncthreads();

    const int l = tid & 63;
    const int ln = l & 15, kq = l >> 4;
    const int row0 = (tid >> 6) * 16;

    f32x4 acc[8];
    #pragma unroll
    for (int n = 0; n < 8; ++n) {
        float b = B1[n * 16 + ln];
        acc[n] = {b, b, b, b};
    }
    {
        const u16* wb = W1t + ln * D + kq * 8;
        #pragma unroll
        for (int kf = 0; kf < 4; ++kf) {
            bf16x8 a = *reinterpret_cast<const bf16x8*>(
                Xc + (row0 + ln) * 256 + ((kf * 64 + kq * 16) ^ ((ln & 7) << 4)));
            #pragma unroll
            for (int n = 0; n < 8; ++n) {
                bf16x8 b = *reinterpret_cast<const bf16x8*>(wb + n * 16 * D + kf * 32);
                acc[n] = __builtin_amdgcn_mfma_f32_16x16x32_bf16(a, b, acc[n], 0, 0, 0);
            }
        }
    }
    #pragma unroll
    for (int n = 0; n < 8; ++n) {
        #pragma unroll
        for (int j = 0; j < 4; ++j) {
            int rl = kq * 4 + j;
            int byte = ((n * 16 + ln) * 2) ^ ((rl & 7) << 4);
            *reinterpret_cast<u16*>(Xc + (row0 + rl) * 256 + byte) =
                f2bf(fmaxf(acc[n][j], 0.f));
        }
    }
    f32x4 acc2[4];
    #pragma unroll
    for (int n = 0; n < 4; ++n) {
        float b = B2[n * 16 + ln];
        acc2[n] = {b, b, b, b};
    }
    {
        const u16* wb = W2t + ln * D + kq * 8;   // W2t is [64][128]
        #pragma unroll
        for (int kf = 0; kf < 4; ++kf) {
            bf16x8 a = *reinterpret_cast<const bf16x8*>(
                Xc + (row0 + ln) * 256 + ((kf * 64 + kq * 16) ^ ((ln & 7) << 4)));
            #pragma unroll
            for (int n = 0; n < 4; ++n) {
                bf16x8 b = *reinterpret_cast<const bf16x8*>(wb + n * 16 * D + kf * 32);
                acc2[n] = __builtin_amdgcn_mfma_f32_16x16x32_bf16(a, b, acc2[n], 0, 0, 0);
            }
        }
    }
    #pragma unroll
    for (int n = 0; n < 4; ++n)
        #pragma unroll
        for (int j = 0; j < 4; ++j) {
            int row = row0 + kq * 4 + j;
            if (row < validRows)
                outp[(long long)(block0 + row) * 64 + n * 16 + ln] = acc2[n][j];
        }
}

extern "C" void kernel_launch(void* const* d_in, const int* in_sizes, int n_in,
                              void* d_out, int out_size, void* d_ws, size_t ws_size,
                              hipStream_t stream) {
    const float* states = (const float*)d_in[0];
    const int* idxp[3] = {(const int*)d_in[1], (const int*)d_in[2], (const int*)d_in[3]};
    const float* rw1[3] = {(const float*)d_in[4], (const float*)d_in[8], (const float*)d_in[12]};
    const float* rb1[3] = {(const float*)d_in[5], (const float*)d_in[9], (const float*)d_in[13]};
    const float* rw2[3] = {(const float*)d_in[6], (const float*)d_in[10], (const float*)d_in[14]};
    const float* rb2[3] = {(const float*)d_in[7], (const float*)d_in[11], (const float*)d_in[15]};
    const float* upw1 = (const float*)d_in[16];
    const float* upb1 = (const float*)d_in[17];
    const float* upw2 = (const float*)d_in[18];
    const float* upb2 = (const float*)d_in[19];

    const int N = in_sizes[0] / 64;
    const int E0 = in_sizes[1] / 1;
    const int E1 = in_sizes[2] / 2;
    const int E2 = in_sizes[3] / 3;
    const int G0 = (E0 + 127) / 128, G1 = (E1 + 127) / 128, G2 = (E2 + 127) / 128;
    const int Gtot = G0 + G1 + G2;
    const int Dd[3] = {64, 128, 192};

    size_t off = 0;
    auto alloc = [&](size_t bytes) {
        void* p = (char*)d_ws + off;
        off += (bytes + 255) & ~(size_t)255;
        return p;
    };
    float* gmaxf = (float*)alloc(4);
    float* blockmax = (float*)alloc((size_t)Gtot * 4);
    __half* exps = (__half*)alloc((size_t)N * 64 * 2);
    u16* statesb = (u16*)alloc((size_t)N * 64 * 2);
    u16* w1t[3], *w2t[3];
    for (int r = 0; r < 3; ++r) {
        w1t[r] = (u16*)alloc((size_t)Dd[r] * Dd[r] * 2);
        w2t[r] = (u16*)alloc((size_t)Dd[r] * Dd[r] * 2);
    }
    u16* upw1t = (u16*)alloc(128 * 128 * 2);
    u16* upw2t = (u16*)alloc(64 * 128 * 2);

    // zero exps only (gmaxf/blockmax fully overwritten every launch)
    (void)hipMemsetAsync(exps, 0, (size_t)N * 64 * 2, stream);

    conv_states<<<dim3((N * 64 / 8 + 255) / 256), dim3(256), 0, stream>>>(
        states, statesb, N * 64 / 8);

    TPack tp;
    const float* tsrc[8] = {rw1[0], rw2[0], rw1[1], rw2[1], rw1[2], rw2[2], upw1, upw2};
    u16* tdst[8] = {w1t[0], w2t[0], w1t[1], w2t[1], w1t[2], w2t[2], upw1t, upw2t};
    const int tK[8] = {64, 64, 128, 128, 192, 192, 128, 128};
    const int tN[8] = {64, 64, 128, 128, 192, 192, 128, 64};
    const float tsc[8] = {1.f, 8.f, 1.f, 8.f, 1.f, 8.f, 1.f, 1.f};
    int base = 0;
    for (int i = 0; i < 8; ++i) {
        tp.e[i] = {tsrc[i], tdst[i], tK[i], tN[i], base, tsc[i]};
        base += (tK[i] * tN[i] + 255) / 256;
    }
    transpose_w<<<dim3(base), dim3(256), 0, stream>>>(tp);

    rel_mfma<64><<<dim3(G0), dim3(256), 0, stream>>>(
        statesb, idxp[0], w1t[0], rb1[0], w2t[0], rb2[0], exps, blockmax, E0);
    rel_mfma<128><<<dim3(G1), dim3(256), 0, stream>>>(
        statesb, idxp[1], w1t[1], rb1[1], w2t[1], rb2[1], exps, blockmax + G0, E1);
    rel_mfma<192><<<dim3(G2), dim3(256), 0, stream>>>(
        statesb, idxp[2], w1t[2], rb1[2], w2t[2], rb2[2], exps, blockmax + G0 + G1, E2);

    reduce_max<<<dim3(1), dim3(256), 0, stream>>>(blockmax, Gtot, gmaxf);

    up_mfma<<<dim3((N + 63) / 64), dim3(256), 0, stream>>>(
        statesb, (const _Float16*)exps, gmaxf, upw1t, upb1, upw2t, upb2,
        (float*)d_out, N);
}

// Round 11
// 542.422 us; speedup vs baseline: 1.3676x; 1.3676x over previous
//
#include <hip/hip_runtime.h>
#include <hip/hip_fp16.h>
#include <math.h>

// RelationMessagePassing — bf16 MFMA, N-split waves (round-9 structure),
// conflict-free gather (linear LDS dest + pre-swizzled global source),
// packed-fp16 atomic scatter.
//
// Round-10 lesson: 128-row tiles killed occupancy (41%->10%, latency-bound
// kernel needs TLP) and its gather swizzled BOTH source and dest (cancels ->
// linear LDS vs swizzled read: wrong-k read, absmax margin shrank 3x).
// This round: exact round-9 structure; gather rewritten so LDS(r,c) holds
// global chunk (c&7)^(r&7) via linear dest + source pre-swizzle (rule #21).
//
// Pipeline: memset exps(fp16) | conv_states | transpose_w (W2 pre-scaled 8) |
//   rel_mfma<64/128/192> (64 tuples/block, wave owns D/4 cols x 64 rows):
//     gather->L1->bar->H->bar->L2 -> blockmax store + pk_f16 atomic exp ->
//   reduce_max | up_mfma: max_msg=log(1e-16+S*e^-8M)/8+M; concat; MFMA; fp32.

typedef __attribute__((ext_vector_type(8))) short bf16x8;
typedef __attribute__((ext_vector_type(4))) float f32x4;
typedef __attribute__((ext_vector_type(8))) _Float16 f16x8;
typedef unsigned short u16;

__device__ __forceinline__ u16 f2bf(float f) {   // RNE f32->bf16 (finite)
    unsigned u = __float_as_uint(f);
    return (u16)((u + 0x7fffu + ((u >> 16) & 1u)) >> 16);
}

// ---------------- prep ----------------
__global__ __launch_bounds__(256) void conv_states(const float* __restrict__ src,
                                                   u16* __restrict__ dst, int n8) {
    int i = blockIdx.x * 256 + threadIdx.x;
    if (i >= n8) return;
    float4 a = reinterpret_cast<const float4*>(src)[2 * i];
    float4 b = reinterpret_cast<const float4*>(src)[2 * i + 1];
    bf16x8 v;
    v[0] = (short)f2bf(a.x); v[1] = (short)f2bf(a.y);
    v[2] = (short)f2bf(a.z); v[3] = (short)f2bf(a.w);
    v[4] = (short)f2bf(b.x); v[5] = (short)f2bf(b.y);
    v[6] = (short)f2bf(b.z); v[7] = (short)f2bf(b.w);
    reinterpret_cast<bf16x8*>(dst)[i] = v;
}

struct TEnt { const float* src; u16* dst; int K, N, base; float scale; };
struct TPack { TEnt e[8]; };
// dst[n*K + k] = bf16(scale * src[k*N + n])
__global__ __launch_bounds__(256) void transpose_w(TPack p) {
    int b = blockIdx.x;
    int i = 0;
    while (i < 7 && b >= p.e[i + 1].base) ++i;
    TEnt e = p.e[i];
    int idx = (b - e.base) * 256 + threadIdx.x;
    if (idx < e.K * e.N) {
        int n = idx / e.K, k = idx - n * e.K;
        e.dst[idx] = f2bf(e.scale * e.src[k * e.N + n]);
    }
}

// ---------------- relation kernels ----------------
// D = arity*64; block = 64 tuples, 4 waves; wave w owns cols [w*D/4,(w+1)*D/4)
// for all 64 rows. Layer2 pre-scaled by 8 => acc' = 8*o.
template <int D>
__global__ __launch_bounds__(256) void rel_mfma(
    const u16* __restrict__ statesb, const int* __restrict__ idx,
    const u16* __restrict__ W1t, const float* __restrict__ B1,
    const u16* __restrict__ W2t, const float* __restrict__ B2,
    __half* __restrict__ exps, float* __restrict__ blockmax, int E) {
    constexpr int A = D / 64;
    constexpr int KF = D / 32;
    constexpr int NFW = D / 64;          // N-frags per wave (D/4 cols)
    constexpr int CPR = D / 8;           // 16B chunks per LDS row
    __shared__ __align__(16) u16 Xs[64 * D];
    __shared__ int Ids[64 * A];
    __shared__ float wmax[4];
    char* Xc = (char*)Xs;

    const int tid = threadIdx.x;
    const int block0 = blockIdx.x * 64;
    const int validRows = min(64, E - block0);
    const int validSegs = validRows * A;
    const long long segBase = (long long)block0 * A;

    // ---- gather: LDS(r, chunk c) must hold global chunk (c&7)^(r&7) of
    // node[c>>3]  (matches the read's XOR un-swizzle). Linear dest q*16 ->
    // consecutive lanes write consecutive 16B -> zero bank conflicts.
    for (int q = tid; q < 64 * CPR; q += 256) {
        int r = q / CPR, c = q - r * CPR;
        int slot = c >> 3;
        int wc = (c & 7) ^ (r & 7);
        int seg = r * A + slot;
        bf16x8 v = {};
        if (seg < validSegs) {
            int node = idx[segBase + seg];
            v = *reinterpret_cast<const bf16x8*>(statesb + (long long)node * 64 + wc * 8);
            if ((c & 7) == 0) Ids[seg] = node;
        }
        *reinterpret_cast<bf16x8*>(Xc + q * 16) = v;
    }
    __syncthreads();

    const int l = tid & 63;
    const int ln = l & 15, kq = l >> 4;
    const int w = tid >> 6;
    const int nbase = w * NFW;           // global N-frag base for this wave

    f32x4 acc[4][NFW];

    // ---- layer 1: h = relu(x@W1 + b1), wave computes its col slice x 64 rows
    #pragma unroll
    for (int nf = 0; nf < NFW; ++nf) {
        float b = B1[(nbase + nf) * 16 + ln];
        #pragma unroll
        for (int m = 0; m < 4; ++m) acc[m][nf] = {b, b, b, b};
    }
    #pragma unroll
    for (int kf = 0; kf < KF; ++kf) {
        bf16x8 a[4];
        #pragma unroll
        for (int m = 0; m < 4; ++m)
            a[m] = *reinterpret_cast<const bf16x8*>(
                Xc + (m * 16 + ln) * (2 * D) + ((kf * 64 + kq * 16) ^ ((ln & 7) << 4)));
        #pragma unroll
        for (int nf = 0; nf < NFW; ++nf) {
            bf16x8 b = *reinterpret_cast<const bf16x8*>(
                W1t + ((nbase + nf) * 16 + ln) * D + kf * 32 + kq * 8);
            #pragma unroll
            for (int m = 0; m < 4; ++m)
                acc[m][nf] = __builtin_amdgcn_mfma_f32_16x16x32_bf16(a[m], b, acc[m][nf], 0, 0, 0);
        }
    }
    __syncthreads();   // all waves done reading X
    // relu -> H (this wave's col slice, all 64 rows)
    #pragma unroll
    for (int nf = 0; nf < NFW; ++nf) {
        const int c = (nbase + nf) * 16 + ln;
        #pragma unroll
        for (int m = 0; m < 4; ++m)
            #pragma unroll
            for (int j = 0; j < 4; ++j) {
                int row = m * 16 + kq * 4 + j;
                int byte = (c * 2) ^ ((row & 7) << 4);
                *reinterpret_cast<u16*>(Xc + row * (2 * D) + byte) =
                    f2bf(fmaxf(acc[m][nf][j], 0.f));
            }
    }
    __syncthreads();   // H complete

    // ---- layer 2 (pre-scaled): acc' = 8*(h@W2 + b2)
    #pragma unroll
    for (int nf = 0; nf < NFW; ++nf) {
        float b = 8.f * B2[(nbase + nf) * 16 + ln];
        #pragma unroll
        for (int m = 0; m < 4; ++m) acc[m][nf] = {b, b, b, b};
    }
    #pragma unroll
    for (int kf = 0; kf < KF; ++kf) {
        bf16x8 a[4];
        #pragma unroll
        for (int m = 0; m < 4; ++m)
            a[m] = *reinterpret_cast<const bf16x8*>(
                Xc + (m * 16 + ln) * (2 * D) + ((kf * 64 + kq * 16) ^ ((ln & 7) << 4)));
        #pragma unroll
        for (int nf = 0; nf < NFW; ++nf) {
            bf16x8 b = *reinterpret_cast<const bf16x8*>(
                W2t + ((nbase + nf) * 16 + ln) * D + kf * 32 + kq * 8);
            #pragma unroll
            for (int m = 0; m < 4; ++m)
                acc[m][nf] = __builtin_amdgcn_mfma_f32_16x16x32_bf16(a[m], b, acc[m][nf], 0, 0, 0);
        }
    }

    // ---- epilogue: block max (plain store) + packed fp16 exp scatter
    float m = -INFINITY;
    #pragma unroll
    for (int mf = 0; mf < 4; ++mf)
        #pragma unroll
        for (int nf = 0; nf < NFW; ++nf)
            #pragma unroll
            for (int j = 0; j < 4; ++j) {
                int row = mf * 16 + kq * 4 + j;
                if (row < validRows) m = fmaxf(m, acc[mf][nf][j]);
            }
    #pragma unroll
    for (int off = 32; off; off >>= 1) m = fmaxf(m, __shfl_xor(m, off));
    if (l == 0) wmax[w] = m;
    __syncthreads();
    if (tid == 0)
        blockmax[blockIdx.x] =
            0.125f * fmaxf(fmaxf(wmax[0], wmax[1]), fmaxf(wmax[2], wmax[3]));

    // even lanes issue one pk_add_f16 covering (feat, feat+1)
    #pragma unroll
    for (int nf = 0; nf < NFW; ++nf) {
        const int c = (nbase + nf) * 16 + ln;
        const int slot = c >> 6;
        const int feat = c & 63;
        #pragma unroll
        for (int mf = 0; mf < 4; ++mf)
            #pragma unroll
            for (int j = 0; j < 4; ++j) {
                int row = mf * 16 + kq * 4 + j;
                float v = __expf(acc[mf][nf][j]);
                float nv = __shfl_xor(v, 1);
                if ((ln & 1) == 0 && row < validRows) {
                    int node = Ids[row * A + slot];
                    __half2 pk = __halves2half2(__float2half(v), __float2half(nv));
                    unsafeAtomicAdd(
                        reinterpret_cast<__half2*>(exps + (long long)node * 64 + feat), pk);
                }
            }
    }
}

// ---------------- global max over block maxima ----------------
__global__ __launch_bounds__(256) void reduce_max(const float* __restrict__ bm,
                                                  int n, float* __restrict__ out) {
    __shared__ float ws_[4];
    float m = -INFINITY;
    for (int i = threadIdx.x; i < n; i += 256) m = fmaxf(m, bm[i]);
    #pragma unroll
    for (int off = 32; off; off >>= 1) m = fmaxf(m, __shfl_xor(m, off));
    if ((threadIdx.x & 63) == 0) ws_[threadIdx.x >> 6] = m;
    __syncthreads();
    if (threadIdx.x == 0)
        out[0] = fmaxf(fmaxf(ws_[0], ws_[1]), fmaxf(ws_[2], ws_[3]));
}

// ---------------- up kernel ----------------
__global__ __launch_bounds__(256) void up_mfma(
    const u16* __restrict__ statesb, const _Float16* __restrict__ exps,
    const float* __restrict__ gmaxp,
    const u16* __restrict__ W1t, const float* __restrict__ B1,
    const u16* __restrict__ W2t, const float* __restrict__ B2,
    float* __restrict__ outp, int Nn) {
    constexpr int D = 128;
    __shared__ __align__(16) u16 Xs[64 * D];
    char* Xc = (char*)Xs;
    const int tid = threadIdx.x;
    const int block0 = blockIdx.x * 64;
    const int validRows = min(64, Nn - block0);
    const float M = gmaxp[0];
    const float EM = __expf(-8.f * M);

    // X tile: cols 0..63 = max_msg, 64..127 = states
    for (int q = tid; q < 64 * 16; q += 256) {
        int r = q >> 4, p = q & 15;
        bf16x8 v = {};
        if (r < validRows) {
            long long nd = block0 + r;
            if (p < 8) {
                f16x8 s = *reinterpret_cast<const f16x8*>(exps + nd * 64 + p * 8);
                #pragma unroll
                for (int i = 0; i < 8; ++i)
                    v[i] = (short)f2bf(__logf(1e-16f + (float)s[i] * EM) * 0.125f + M);
            } else {
                v = *reinterpret_cast<const bf16x8*>(statesb + nd * 64 + (p - 8) * 8);
            }
        }
        int byte = (p * 16) ^ ((r & 7) << 4);
        *reinterpret_cast<bf16x8*>(Xc + r * 256 + byte) = v;
    }
    __syncthreads();

    const int l = tid & 63;
    const int ln = l & 15, kq = l >> 4;
    const int row0 = (tid >> 6) * 16;

    f32x4 acc[8];
    #pragma unroll
    for (int n = 0; n < 8; ++n) {
        float b = B1[n * 16 + ln];
        acc[n] = {b, b, b, b};
    }
    {
        const u16* wb = W1t + ln * D + kq * 8;
        #pragma unroll
        for (int kf = 0; kf < 4; ++kf) {
            bf16x8 a = *reinterpret_cast<const bf16x8*>(
                Xc + (row0 + ln) * 256 + ((kf * 64 + kq * 16) ^ ((ln & 7) << 4)));
            #pragma unroll
            for (int n = 0; n < 8; ++n) {
                bf16x8 b = *reinterpret_cast<const bf16x8*>(wb + n * 16 * D + kf * 32);
                acc[n] = __builtin_amdgcn_mfma_f32_16x16x32_bf16(a, b, acc[n], 0, 0, 0);
            }
        }
    }
    #pragma unroll
    for (int n = 0; n < 8; ++n) {
        #pragma unroll
        for (int j = 0; j < 4; ++j) {
            int rl = kq * 4 + j;
            int byte = ((n * 16 + ln) * 2) ^ ((rl & 7) << 4);
            *reinterpret_cast<u16*>(Xc + (row0 + rl) * 256 + byte) =
                f2bf(fmaxf(acc[n][j], 0.f));
        }
    }
    f32x4 acc2[4];
    #pragma unroll
    for (int n = 0; n < 4; ++n) {
        float b = B2[n * 16 + ln];
        acc2[n] = {b, b, b, b};
    }
    {
        const u16* wb = W2t + ln * D + kq * 8;   // W2t is [64][128]
        #pragma unroll
        for (int kf = 0; kf < 4; ++kf) {
            bf16x8 a = *reinterpret_cast<const bf16x8*>(
                Xc + (row0 + ln) * 256 + ((kf * 64 + kq * 16) ^ ((ln & 7) << 4)));
            #pragma unroll
            for (int n = 0; n < 4; ++n) {
                bf16x8 b = *reinterpret_cast<const bf16x8*>(wb + n * 16 * D + kf * 32);
                acc2[n] = __builtin_amdgcn_mfma_f32_16x16x32_bf16(a, b, acc2[n], 0, 0, 0);
            }
        }
    }
    #pragma unroll
    for (int n = 0; n < 4; ++n)
        #pragma unroll
        for (int j = 0; j < 4; ++j) {
            int row = row0 + kq * 4 + j;
            if (row < validRows)
                outp[(long long)(block0 + row) * 64 + n * 16 + ln] = acc2[n][j];
        }
}

extern "C" void kernel_launch(void* const* d_in, const int* in_sizes, int n_in,
                              void* d_out, int out_size, void* d_ws, size_t ws_size,
                              hipStream_t stream) {
    const float* states = (const float*)d_in[0];
    const int* idxp[3] = {(const int*)d_in[1], (const int*)d_in[2], (const int*)d_in[3]};
    const float* rw1[3] = {(const float*)d_in[4], (const float*)d_in[8], (const float*)d_in[12]};
    const float* rb1[3] = {(const float*)d_in[5], (const float*)d_in[9], (const float*)d_in[13]};
    const float* rw2[3] = {(const float*)d_in[6], (const float*)d_in[10], (const float*)d_in[14]};
    const float* rb2[3] = {(const float*)d_in[7], (const float*)d_in[11], (const float*)d_in[15]};
    const float* upw1 = (const float*)d_in[16];
    const float* upb1 = (const float*)d_in[17];
    const float* upw2 = (const float*)d_in[18];
    const float* upb2 = (const float*)d_in[19];

    const int N = in_sizes[0] / 64;
    const int E0 = in_sizes[1] / 1;
    const int E1 = in_sizes[2] / 2;
    const int E2 = in_sizes[3] / 3;
    const int G0 = (E0 + 63) / 64, G1 = (E1 + 63) / 64, G2 = (E2 + 63) / 64;
    const int Gtot = G0 + G1 + G2;
    const int Dd[3] = {64, 128, 192};

    size_t off = 0;
    auto alloc = [&](size_t bytes) {
        void* p = (char*)d_ws + off;
        off += (bytes + 255) & ~(size_t)255;
        return p;
    };
    float* gmaxf = (float*)alloc(4);
    float* blockmax = (float*)alloc((size_t)Gtot * 4);
    __half* exps = (__half*)alloc((size_t)N * 64 * 2);
    u16* statesb = (u16*)alloc((size_t)N * 64 * 2);
    u16* w1t[3], *w2t[3];
    for (int r = 0; r < 3; ++r) {
        w1t[r] = (u16*)alloc((size_t)Dd[r] * Dd[r] * 2);
        w2t[r] = (u16*)alloc((size_t)Dd[r] * Dd[r] * 2);
    }
    u16* upw1t = (u16*)alloc(128 * 128 * 2);
    u16* upw2t = (u16*)alloc(64 * 128 * 2);

    // zero exps only (gmaxf/blockmax fully overwritten every launch)
    (void)hipMemsetAsync(exps, 0, (size_t)N * 64 * 2, stream);

    conv_states<<<dim3((N * 64 / 8 + 255) / 256), dim3(256), 0, stream>>>(
        states, statesb, N * 64 / 8);

    TPack tp;
    const float* tsrc[8] = {rw1[0], rw2[0], rw1[1], rw2[1], rw1[2], rw2[2], upw1, upw2};
    u16* tdst[8] = {w1t[0], w2t[0], w1t[1], w2t[1], w1t[2], w2t[2], upw1t, upw2t};
    const int tK[8] = {64, 64, 128, 128, 192, 192, 128, 128};
    const int tN[8] = {64, 64, 128, 128, 192, 192, 128, 64};
    const float tsc[8] = {1.f, 8.f, 1.f, 8.f, 1.f, 8.f, 1.f, 1.f};
    int base = 0;
    for (int i = 0; i < 8; ++i) {
        tp.e[i] = {tsrc[i], tdst[i], tK[i], tN[i], base, tsc[i]};
        base += (tK[i] * tN[i] + 255) / 256;
    }
    transpose_w<<<dim3(base), dim3(256), 0, stream>>>(tp);

    rel_mfma<64><<<dim3(G0), dim3(256), 0, stream>>>(
        statesb, idxp[0], w1t[0], rb1[0], w2t[0], rb2[0], exps, blockmax, E0);
    rel_mfma<128><<<dim3(G1), dim3(256), 0, stream>>>(
        statesb, idxp[1], w1t[1], rb1[1], w2t[1], rb2[1], exps, blockmax + G0, E1);
    rel_mfma<192><<<dim3(G2), dim3(256), 0, stream>>>(
        statesb, idxp[2], w1t[2], rb1[2], w2t[2], rb2[2], exps, blockmax + G0 + G1, E2);

    reduce_max<<<dim3(1), dim3(256), 0, stream>>>(blockmax, Gtot, gmaxf);

    up_mfma<<<dim3((N + 63) / 64), dim3(256), 0, stream>>>(
        statesb, (const _Float16*)exps, gmaxf, upw1t, upb1, upw2t, upb2,
        (float*)d_out, N);
}

// Round 12
// 500.547 us; speedup vs baseline: 1.4820x; 1.0837x over previous
//
#include <hip/hip_runtime.h>
#include <hip/hip_fp16.h>
#include <math.h>

// RelationMessagePassing — bf16 MFMA, N-split waves, FUSED rel kernel
// (all 3 relations in one grid), packed-fp16 atomic scatter.
//
// Round-11 findings: (1) 3.2M LDS conflicts are from the MFMA-phase reads,
// not gather, and are off the critical path (fixing gather changed nothing);
// (2) rel kernels are latency chains at ~3 blocks/CU with NO saturated pipe,
// run sequentially (~435 us of 542). This round fuses rel64/128/192 into one
// launch so the three latency-bound phases overlap and two launch tails die.
//
// Pipeline: memset exps(fp16) | conv_states | transpose_w (W2 pre-scaled 8) |
//   rel_fused (block-range dispatch -> rel_body<64/128/192>):
//     gather(linear dest, pre-swizzled src)->L1->bar->H->bar->L2 ->
//     blockmax[bid] store + pk_f16 atomic exp(acc') |
//   reduce_max | up_mfma: max_msg=log(1e-16+S*e^-8M)/8+M; concat; MFMA; fp32.

typedef __attribute__((ext_vector_type(8))) short bf16x8;
typedef __attribute__((ext_vector_type(4))) float f32x4;
typedef __attribute__((ext_vector_type(8))) _Float16 f16x8;
typedef unsigned short u16;

__device__ __forceinline__ u16 f2bf(float f) {   // RNE f32->bf16 (finite)
    unsigned u = __float_as_uint(f);
    return (u16)((u + 0x7fffu + ((u >> 16) & 1u)) >> 16);
}

// ---------------- prep ----------------
__global__ __launch_bounds__(256) void conv_states(const float* __restrict__ src,
                                                   u16* __restrict__ dst, int n8) {
    int i = blockIdx.x * 256 + threadIdx.x;
    if (i >= n8) return;
    float4 a = reinterpret_cast<const float4*>(src)[2 * i];
    float4 b = reinterpret_cast<const float4*>(src)[2 * i + 1];
    bf16x8 v;
    v[0] = (short)f2bf(a.x); v[1] = (short)f2bf(a.y);
    v[2] = (short)f2bf(a.z); v[3] = (short)f2bf(a.w);
    v[4] = (short)f2bf(b.x); v[5] = (short)f2bf(b.y);
    v[6] = (short)f2bf(b.z); v[7] = (short)f2bf(b.w);
    reinterpret_cast<bf16x8*>(dst)[i] = v;
}

struct TEnt { const float* src; u16* dst; int K, N, base; float scale; };
struct TPack { TEnt e[8]; };
// dst[n*K + k] = bf16(scale * src[k*N + n])
__global__ __launch_bounds__(256) void transpose_w(TPack p) {
    int b = blockIdx.x;
    int i = 0;
    while (i < 7 && b >= p.e[i + 1].base) ++i;
    TEnt e = p.e[i];
    int idx = (b - e.base) * 256 + threadIdx.x;
    if (idx < e.K * e.N) {
        int n = idx / e.K, k = idx - n * e.K;
        e.dst[idx] = f2bf(e.scale * e.src[k * e.N + n]);
    }
}

// ---------------- fused relation kernel ----------------
// D = arity*64; block = 64 tuples, 4 waves; wave w owns cols [w*D/4,(w+1)*D/4)
// for all 64 rows. Layer2 pre-scaled by 8 => acc' = 8*o.
template <int D>
__device__ __forceinline__ void rel_body(
    const u16* __restrict__ statesb, const int* __restrict__ idx,
    const u16* __restrict__ W1t, const float* __restrict__ B1,
    const u16* __restrict__ W2t, const float* __restrict__ B2,
    __half* __restrict__ exps, float* __restrict__ bmslot, int E, int bid,
    u16* Xs, int* Ids, float* wmax) {
    constexpr int A = D / 64;
    constexpr int KF = D / 32;
    constexpr int NFW = D / 64;          // N-frags per wave (D/4 cols)
    constexpr int CPR = D / 8;           // 16B chunks per LDS row
    char* Xc = (char*)Xs;

    const int tid = threadIdx.x;
    const int block0 = bid * 64;
    const int validRows = min(64, E - block0);
    const int validSegs = validRows * A;
    const long long segBase = (long long)block0 * A;

    // gather: LDS(r, chunk c) holds global chunk (c&7)^(r&7) of node[c>>3]
    // (matches the read's XOR un-swizzle). Linear dest -> no write conflicts.
    for (int q = tid; q < 64 * CPR; q += 256) {
        int r = q / CPR, c = q - r * CPR;
        int slot = c >> 3;
        int wc = (c & 7) ^ (r & 7);
        int seg = r * A + slot;
        bf16x8 v = {};
        if (seg < validSegs) {
            int node = idx[segBase + seg];
            v = *reinterpret_cast<const bf16x8*>(statesb + (long long)node * 64 + wc * 8);
            if ((c & 7) == 0) Ids[seg] = node;
        }
        *reinterpret_cast<bf16x8*>(Xc + q * 16) = v;
    }
    __syncthreads();

    const int l = tid & 63;
    const int ln = l & 15, kq = l >> 4;
    const int w = tid >> 6;
    const int nbase = w * NFW;

    f32x4 acc[4][NFW];

    // ---- layer 1: h = relu(x@W1 + b1)
    #pragma unroll
    for (int nf = 0; nf < NFW; ++nf) {
        float b = B1[(nbase + nf) * 16 + ln];
        #pragma unroll
        for (int m = 0; m < 4; ++m) acc[m][nf] = {b, b, b, b};
    }
    #pragma unroll
    for (int kf = 0; kf < KF; ++kf) {
        bf16x8 a[4];
        #pragma unroll
        for (int m = 0; m < 4; ++m)
            a[m] = *reinterpret_cast<const bf16x8*>(
                Xc + (m * 16 + ln) * (2 * D) + ((kf * 64 + kq * 16) ^ ((ln & 7) << 4)));
        #pragma unroll
        for (int nf = 0; nf < NFW; ++nf) {
            bf16x8 b = *reinterpret_cast<const bf16x8*>(
                W1t + ((nbase + nf) * 16 + ln) * D + kf * 32 + kq * 8);
            #pragma unroll
            for (int m = 0; m < 4; ++m)
                acc[m][nf] = __builtin_amdgcn_mfma_f32_16x16x32_bf16(a[m], b, acc[m][nf], 0, 0, 0);
        }
    }
    __syncthreads();
    // relu -> H (this wave's col slice, all 64 rows)
    #pragma unroll
    for (int nf = 0; nf < NFW; ++nf) {
        const int c = (nbase + nf) * 16 + ln;
        #pragma unroll
        for (int m = 0; m < 4; ++m)
            #pragma unroll
            for (int j = 0; j < 4; ++j) {
                int row = m * 16 + kq * 4 + j;
                int byte = (c * 2) ^ ((row & 7) << 4);
                *reinterpret_cast<u16*>(Xc + row * (2 * D) + byte) =
                    f2bf(fmaxf(acc[m][nf][j], 0.f));
            }
    }
    __syncthreads();

    // ---- layer 2 (pre-scaled): acc' = 8*(h@W2 + b2)
    #pragma unroll
    for (int nf = 0; nf < NFW; ++nf) {
        float b = 8.f * B2[(nbase + nf) * 16 + ln];
        #pragma unroll
        for (int m = 0; m < 4; ++m) acc[m][nf] = {b, b, b, b};
    }
    #pragma unroll
    for (int kf = 0; kf < KF; ++kf) {
        bf16x8 a[4];
        #pragma unroll
        for (int m = 0; m < 4; ++m)
            a[m] = *reinterpret_cast<const bf16x8*>(
                Xc + (m * 16 + ln) * (2 * D) + ((kf * 64 + kq * 16) ^ ((ln & 7) << 4)));
        #pragma unroll
        for (int nf = 0; nf < NFW; ++nf) {
            bf16x8 b = *reinterpret_cast<const bf16x8*>(
                W2t + ((nbase + nf) * 16 + ln) * D + kf * 32 + kq * 8);
            #pragma unroll
            for (int m = 0; m < 4; ++m)
                acc[m][nf] = __builtin_amdgcn_mfma_f32_16x16x32_bf16(a[m], b, acc[m][nf], 0, 0, 0);
        }
    }

    // ---- epilogue: block max (plain store) + packed fp16 exp scatter
    float m = -INFINITY;
    #pragma unroll
    for (int mf = 0; mf < 4; ++mf)
        #pragma unroll
        for (int nf = 0; nf < NFW; ++nf)
            #pragma unroll
            for (int j = 0; j < 4; ++j) {
                int row = mf * 16 + kq * 4 + j;
                if (row < validRows) m = fmaxf(m, acc[mf][nf][j]);
            }
    #pragma unroll
    for (int off = 32; off; off >>= 1) m = fmaxf(m, __shfl_xor(m, off));
    if (l == 0) wmax[w] = m;
    __syncthreads();
    if (tid == 0)
        *bmslot = 0.125f * fmaxf(fmaxf(wmax[0], wmax[1]), fmaxf(wmax[2], wmax[3]));

    // even lanes issue one pk_add_f16 covering (feat, feat+1)
    #pragma unroll
    for (int nf = 0; nf < NFW; ++nf) {
        const int c = (nbase + nf) * 16 + ln;
        const int slot = c >> 6;
        const int feat = c & 63;
        #pragma unroll
        for (int mf = 0; mf < 4; ++mf)
            #pragma unroll
            for (int j = 0; j < 4; ++j) {
                int row = mf * 16 + kq * 4 + j;
                float v = __expf(acc[mf][nf][j]);
                float nv = __shfl_xor(v, 1);
                if ((ln & 1) == 0 && row < validRows) {
                    int node = Ids[row * A + slot];
                    __half2 pk = __halves2half2(__float2half(v), __float2half(nv));
                    unsafeAtomicAdd(
                        reinterpret_cast<__half2*>(exps + (long long)node * 64 + feat), pk);
                }
            }
    }
}

struct RelArgs {
    const u16* statesb;
    const int* idx0; const int* idx1; const int* idx2;
    const u16* w1t0; const float* b10; const u16* w2t0; const float* b20;
    const u16* w1t1; const float* b11; const u16* w2t1; const float* b21;
    const u16* w1t2; const float* b12; const u16* w2t2; const float* b22;
    __half* exps;
    float* blockmax;
    int E0, E1, E2, G0, G01;   // G01 = G0+G1
};

__global__ __launch_bounds__(256) void rel_fused(RelArgs a) {
    __shared__ __align__(16) u16 Xs[64 * 192];
    __shared__ int Ids[64 * 3];
    __shared__ float wmax[4];
    const int bid = blockIdx.x;
    if (bid < a.G0)
        rel_body<64>(a.statesb, a.idx0, a.w1t0, a.b10, a.w2t0, a.b20,
                     a.exps, a.blockmax + bid, a.E0, bid, Xs, Ids, wmax);
    else if (bid < a.G01)
        rel_body<128>(a.statesb, a.idx1, a.w1t1, a.b11, a.w2t1, a.b21,
                      a.exps, a.blockmax + bid, a.E1, bid - a.G0, Xs, Ids, wmax);
    else
        rel_body<192>(a.statesb, a.idx2, a.w1t2, a.b12, a.w2t2, a.b22,
                      a.exps, a.blockmax + bid, a.E2, bid - a.G01, Xs, Ids, wmax);
}

// ---------------- global max over block maxima ----------------
__global__ __launch_bounds__(256) void reduce_max(const float* __restrict__ bm,
                                                  int n, float* __restrict__ out) {
    __shared__ float ws_[4];
    float m = -INFINITY;
    for (int i = threadIdx.x; i < n; i += 256) m = fmaxf(m, bm[i]);
    #pragma unroll
    for (int off = 32; off; off >>= 1) m = fmaxf(m, __shfl_xor(m, off));
    if ((threadIdx.x & 63) == 0) ws_[threadIdx.x >> 6] = m;
    __syncthreads();
    if (threadIdx.x == 0)
        out[0] = fmaxf(fmaxf(ws_[0], ws_[1]), fmaxf(ws_[2], ws_[3]));
}

// ---------------- up kernel ----------------
__global__ __launch_bounds__(256) void up_mfma(
    const u16* __restrict__ statesb, const _Float16* __restrict__ exps,
    const float* __restrict__ gmaxp,
    const u16* __restrict__ W1t, const float* __restrict__ B1,
    const u16* __restrict__ W2t, const float* __restrict__ B2,
    float* __restrict__ outp, int Nn) {
    constexpr int D = 128;
    __shared__ __align__(16) u16 Xs[64 * D];
    char* Xc = (char*)Xs;
    const int tid = threadIdx.x;
    const int block0 = blockIdx.x * 64;
    const int validRows = min(64, Nn - block0);
    const float M = gmaxp[0];
    const float EM = __expf(-8.f * M);

    // X tile: cols 0..63 = max_msg, 64..127 = states
    for (int q = tid; q < 64 * 16; q += 256) {
        int r = q >> 4, p = q & 15;
        bf16x8 v = {};
        if (r < validRows) {
            long long nd = block0 + r;
            if (p < 8) {
                f16x8 s = *reinterpret_cast<const f16x8*>(exps + nd * 64 + p * 8);
                #pragma unroll
                for (int i = 0; i < 8; ++i)
                    v[i] = (short)f2bf(__logf(1e-16f + (float)s[i] * EM) * 0.125f + M);
            } else {
                v = *reinterpret_cast<const bf16x8*>(statesb + nd * 64 + (p - 8) * 8);
            }
        }
        int byte = (p * 16) ^ ((r & 7) << 4);
        *reinterpret_cast<bf16x8*>(Xc + r * 256 + byte) = v;
    }
    __syncthreads();

    const int l = tid & 63;
    const int ln = l & 15, kq = l >> 4;
    const int row0 = (tid >> 6) * 16;

    f32x4 acc[8];
    #pragma unroll
    for (int n = 0; n < 8; ++n) {
        float b = B1[n * 16 + ln];
        acc[n] = {b, b, b, b};
    }
    {
        const u16* wb = W1t + ln * D + kq * 8;
        #pragma unroll
        for (int kf = 0; kf < 4; ++kf) {
            bf16x8 a = *reinterpret_cast<const bf16x8*>(
                Xc + (row0 + ln) * 256 + ((kf * 64 + kq * 16) ^ ((ln & 7) << 4)));
            #pragma unroll
            for (int n = 0; n < 8; ++n) {
                bf16x8 b = *reinterpret_cast<const bf16x8*>(wb + n * 16 * D + kf * 32);
                acc[n] = __builtin_amdgcn_mfma_f32_16x16x32_bf16(a, b, acc[n], 0, 0, 0);
            }
        }
    }
    #pragma unroll
    for (int n = 0; n < 8; ++n) {
        #pragma unroll
        for (int j = 0; j < 4; ++j) {
            int rl = kq * 4 + j;
            int byte = ((n * 16 + ln) * 2) ^ ((rl & 7) << 4);
            *reinterpret_cast<u16*>(Xc + (row0 + rl) * 256 + byte) =
                f2bf(fmaxf(acc[n][j], 0.f));
        }
    }
    f32x4 acc2[4];
    #pragma unroll
    for (int n = 0; n < 4; ++n) {
        float b = B2[n * 16 + ln];
        acc2[n] = {b, b, b, b};
    }
    {
        const u16* wb = W2t + ln * D + kq * 8;   // W2t is [64][128]
        #pragma unroll
        for (int kf = 0; kf < 4; ++kf) {
            bf16x8 a = *reinterpret_cast<const bf16x8*>(
                Xc + (row0 + ln) * 256 + ((kf * 64 + kq * 16) ^ ((ln & 7) << 4)));
            #pragma unroll
            for (int n = 0; n < 4; ++n) {
                bf16x8 b = *reinterpret_cast<const bf16x8*>(wb + n * 16 * D + kf * 32);
                acc2[n] = __builtin_amdgcn_mfma_f32_16x16x32_bf16(a, b, acc2[n], 0, 0, 0);
            }
        }
    }
    #pragma unroll
    for (int n = 0; n < 4; ++n)
        #pragma unroll
        for (int j = 0; j < 4; ++j) {
            int row = row0 + kq * 4 + j;
            if (row < validRows)
                outp[(long long)(block0 + row) * 64 + n * 16 + ln] = acc2[n][j];
        }
}

extern "C" void kernel_launch(void* const* d_in, const int* in_sizes, int n_in,
                              void* d_out, int out_size, void* d_ws, size_t ws_size,
                              hipStream_t stream) {
    const float* states = (const float*)d_in[0];
    const int* idxp[3] = {(const int*)d_in[1], (const int*)d_in[2], (const int*)d_in[3]};
    const float* rw1[3] = {(const float*)d_in[4], (const float*)d_in[8], (const float*)d_in[12]};
    const float* rb1[3] = {(const float*)d_in[5], (const float*)d_in[9], (const float*)d_in[13]};
    const float* rw2[3] = {(const float*)d_in[6], (const float*)d_in[10], (const float*)d_in[14]};
    const float* rb2[3] = {(const float*)d_in[7], (const float*)d_in[11], (const float*)d_in[15]};
    const float* upw1 = (const float*)d_in[16];
    const float* upb1 = (const float*)d_in[17];
    const float* upw2 = (const float*)d_in[18];
    const float* upb2 = (const float*)d_in[19];

    const int N = in_sizes[0] / 64;
    const int E0 = in_sizes[1] / 1;
    const int E1 = in_sizes[2] / 2;
    const int E2 = in_sizes[3] / 3;
    const int G0 = (E0 + 63) / 64, G1 = (E1 + 63) / 64, G2 = (E2 + 63) / 64;
    const int Gtot = G0 + G1 + G2;
    const int Dd[3] = {64, 128, 192};

    size_t off = 0;
    auto alloc = [&](size_t bytes) {
        void* p = (char*)d_ws + off;
        off += (bytes + 255) & ~(size_t)255;
        return p;
    };
    float* gmaxf = (float*)alloc(4);
    float* blockmax = (float*)alloc((size_t)Gtot * 4);
    __half* exps = (__half*)alloc((size_t)N * 64 * 2);
    u16* statesb = (u16*)alloc((size_t)N * 64 * 2);
    u16* w1t[3], *w2t[3];
    for (int r = 0; r < 3; ++r) {
        w1t[r] = (u16*)alloc((size_t)Dd[r] * Dd[r] * 2);
        w2t[r] = (u16*)alloc((size_t)Dd[r] * Dd[r] * 2);
    }
    u16* upw1t = (u16*)alloc(128 * 128 * 2);
    u16* upw2t = (u16*)alloc(64 * 128 * 2);

    // zero exps only (gmaxf/blockmax fully overwritten every launch)
    (void)hipMemsetAsync(exps, 0, (size_t)N * 64 * 2, stream);

    conv_states<<<dim3((N * 64 / 8 + 255) / 256), dim3(256), 0, stream>>>(
        states, statesb, N * 64 / 8);

    TPack tp;
    const float* tsrc[8] = {rw1[0], rw2[0], rw1[1], rw2[1], rw1[2], rw2[2], upw1, upw2};
    u16* tdst[8] = {w1t[0], w2t[0], w1t[1], w2t[1], w1t[2], w2t[2], upw1t, upw2t};
    const int tK[8] = {64, 64, 128, 128, 192, 192, 128, 128};
    const int tN[8] = {64, 64, 128, 128, 192, 192, 128, 64};
    const float tsc[8] = {1.f, 8.f, 1.f, 8.f, 1.f, 8.f, 1.f, 1.f};
    int base = 0;
    for (int i = 0; i < 8; ++i) {
        tp.e[i] = {tsrc[i], tdst[i], tK[i], tN[i], base, tsc[i]};
        base += (tK[i] * tN[i] + 255) / 256;
    }
    transpose_w<<<dim3(base), dim3(256), 0, stream>>>(tp);

    RelArgs ra;
    ra.statesb = statesb;
    ra.idx0 = idxp[0]; ra.idx1 = idxp[1]; ra.idx2 = idxp[2];
    ra.w1t0 = w1t[0]; ra.b10 = rb1[0]; ra.w2t0 = w2t[0]; ra.b20 = rb2[0];
    ra.w1t1 = w1t[1]; ra.b11 = rb1[1]; ra.w2t1 = w2t[1]; ra.b21 = rb2[1];
    ra.w1t2 = w1t[2]; ra.b12 = rb1[2]; ra.w2t2 = w2t[2]; ra.b22 = rb2[2];
    ra.exps = exps;
    ra.blockmax = blockmax;
    ra.E0 = E0; ra.E1 = E1; ra.E2 = E2; ra.G0 = G0; ra.G01 = G0 + G1;

    rel_fused<<<dim3(Gtot), dim3(256), 0, stream>>>(ra);

    reduce_max<<<dim3(1), dim3(256), 0, stream>>>(blockmax, Gtot, gmaxf);

    up_mfma<<<dim3((N + 63) / 64), dim3(256), 0, stream>>>(
        statesb, (const _Float16*)exps, gmaxf, upw1t, upb1, upw2t, upb2,
        (float*)d_out, N);
}

// Round 14
// 440.320 us; speedup vs baseline: 1.6847x; 1.1368x over previous
//
#include <hip/hip_runtime.h>
#include <hip/hip_fp16.h>
#include <math.h>

// RelationMessagePassing — bf16 MFMA, fused rel kernel with DEDUPED arity-1
// relation, packed-fp16 atomic scatter.  (Resubmit: round-13 infra failure.)
//
// Round-12 finding: time = counted-memory-bytes / ~790 GB/s for every config
// (random gather + atomic write-through mix); fusion didn't overlap because
// the byte pipe is saturated. Lever = fewer bytes. Arity-1 messages are a
// pure function of the node (500k participants, only ~100k unique nodes,
// mean multiplicity 5): histogram idx0 -> process each node ONCE with
// streaming gather, scatter cnt*exp(8*o) (exact vs cnt separate adds).
// r0 atomic bytes 64->12.7 MB, r0 gather random->streaming, r0 compute /5.
//
// Pipeline: memset(exps+hist0) | conv_states | transpose_w (W2 pre-scaled 8) |
//   hist_k(idx0) | rel_fused: [r0-dedup | rel<128> | rel<192>] ->
//     blockmax[bid] + pk_f16 atomics | reduce_max | up_mfma -> fp32 out.

typedef __attribute__((ext_vector_type(8))) short bf16x8;
typedef __attribute__((ext_vector_type(4))) float f32x4;
typedef __attribute__((ext_vector_type(8))) _Float16 f16x8;
typedef unsigned short u16;

__device__ __forceinline__ u16 f2bf(float f) {   // RNE f32->bf16 (finite)
    unsigned u = __float_as_uint(f);
    return (u16)((u + 0x7fffu + ((u >> 16) & 1u)) >> 16);
}

// ---------------- prep ----------------
__global__ __launch_bounds__(256) void conv_states(const float* __restrict__ src,
                                                   u16* __restrict__ dst, int n8) {
    int i = blockIdx.x * 256 + threadIdx.x;
    if (i >= n8) return;
    float4 a = reinterpret_cast<const float4*>(src)[2 * i];
    float4 b = reinterpret_cast<const float4*>(src)[2 * i + 1];
    bf16x8 v;
    v[0] = (short)f2bf(a.x); v[1] = (short)f2bf(a.y);
    v[2] = (short)f2bf(a.z); v[3] = (short)f2bf(a.w);
    v[4] = (short)f2bf(b.x); v[5] = (short)f2bf(b.y);
    v[6] = (short)f2bf(b.z); v[7] = (short)f2bf(b.w);
    reinterpret_cast<bf16x8*>(dst)[i] = v;
}

struct TEnt { const float* src; u16* dst; int K, N, base; float scale; };
struct TPack { TEnt e[8]; };
// dst[n*K + k] = bf16(scale * src[k*N + n])
__global__ __launch_bounds__(256) void transpose_w(TPack p) {
    int b = blockIdx.x;
    int i = 0;
    while (i < 7 && b >= p.e[i + 1].base) ++i;
    TEnt e = p.e[i];
    int idx = (b - e.base) * 256 + threadIdx.x;
    if (idx < e.K * e.N) {
        int n = idx / e.K, k = idx - n * e.K;
        e.dst[idx] = f2bf(e.scale * e.src[k * e.N + n]);
    }
}

__global__ __launch_bounds__(256) void hist_k(const int* __restrict__ idx, int n,
                                              int* __restrict__ hist) {
    int i = blockIdx.x * 256 + threadIdx.x;
    if (i < n) atomicAdd(&hist[idx[i]], 1);
}

// ---------------- relation bodies ----------------
// Generic (arity 2/3): block = 64 tuples, 4 waves; wave w owns cols
// [w*D/4,(w+1)*D/4) x all 64 rows. Layer2 pre-scaled by 8 => acc' = 8*o.
template <int D>
__device__ __forceinline__ void rel_body(
    const u16* __restrict__ statesb, const int* __restrict__ idx,
    const u16* __restrict__ W1t, const float* __restrict__ B1,
    const u16* __restrict__ W2t, const float* __restrict__ B2,
    __half* __restrict__ exps, float* __restrict__ bmslot, int E, int bid,
    u16* Xs, int* Ids, float* wmax) {
    constexpr int A = D / 64;
    constexpr int KF = D / 32;
    constexpr int NFW = D / 64;
    constexpr int CPR = D / 8;
    char* Xc = (char*)Xs;

    const int tid = threadIdx.x;
    const int block0 = bid * 64;
    const int validRows = min(64, E - block0);
    const int validSegs = validRows * A;
    const long long segBase = (long long)block0 * A;

    // gather: LDS(r,c) holds global chunk (c&7)^(r&7) of node[c>>3]
    for (int q = tid; q < 64 * CPR; q += 256) {
        int r = q / CPR, c = q - r * CPR;
        int slot = c >> 3;
        int wc = (c & 7) ^ (r & 7);
        int seg = r * A + slot;
        bf16x8 v = {};
        if (seg < validSegs) {
            int node = idx[segBase + seg];
            v = *reinterpret_cast<const bf16x8*>(statesb + (long long)node * 64 + wc * 8);
            if ((c & 7) == 0) Ids[seg] = node;
        }
        *reinterpret_cast<bf16x8*>(Xc + q * 16) = v;
    }
    __syncthreads();

    const int l = tid & 63;
    const int ln = l & 15, kq = l >> 4;
    const int w = tid >> 6;
    const int nbase = w * NFW;

    f32x4 acc[4][NFW];

    // layer 1
    #pragma unroll
    for (int nf = 0; nf < NFW; ++nf) {
        float b = B1[(nbase + nf) * 16 + ln];
        #pragma unroll
        for (int m = 0; m < 4; ++m) acc[m][nf] = {b, b, b, b};
    }
    #pragma unroll
    for (int kf = 0; kf < KF; ++kf) {
        bf16x8 a[4];
        #pragma unroll
        for (int m = 0; m < 4; ++m)
            a[m] = *reinterpret_cast<const bf16x8*>(
                Xc + (m * 16 + ln) * (2 * D) + ((kf * 64 + kq * 16) ^ ((ln & 7) << 4)));
        #pragma unroll
        for (int nf = 0; nf < NFW; ++nf) {
            bf16x8 b = *reinterpret_cast<const bf16x8*>(
                W1t + ((nbase + nf) * 16 + ln) * D + kf * 32 + kq * 8);
            #pragma unroll
            for (int m = 0; m < 4; ++m)
                acc[m][nf] = __builtin_amdgcn_mfma_f32_16x16x32_bf16(a[m], b, acc[m][nf], 0, 0, 0);
        }
    }
    __syncthreads();
    // relu -> H
    #pragma unroll
    for (int nf = 0; nf < NFW; ++nf) {
        const int c = (nbase + nf) * 16 + ln;
        #pragma unroll
        for (int m = 0; m < 4; ++m)
            #pragma unroll
            for (int j = 0; j < 4; ++j) {
                int row = m * 16 + kq * 4 + j;
                int byte = (c * 2) ^ ((row & 7) << 4);
                *reinterpret_cast<u16*>(Xc + row * (2 * D) + byte) =
                    f2bf(fmaxf(acc[m][nf][j], 0.f));
            }
    }
    __syncthreads();

    // layer 2 (pre-scaled by 8)
    #pragma unroll
    for (int nf = 0; nf < NFW; ++nf) {
        float b = 8.f * B2[(nbase + nf) * 16 + ln];
        #pragma unroll
        for (int m = 0; m < 4; ++m) acc[m][nf] = {b, b, b, b};
    }
    #pragma unroll
    for (int kf = 0; kf < KF; ++kf) {
        bf16x8 a[4];
        #pragma unroll
        for (int m = 0; m < 4; ++m)
            a[m] = *reinterpret_cast<const bf16x8*>(
                Xc + (m * 16 + ln) * (2 * D) + ((kf * 64 + kq * 16) ^ ((ln & 7) << 4)));
        #pragma unroll
        for (int nf = 0; nf < NFW; ++nf) {
            bf16x8 b = *reinterpret_cast<const bf16x8*>(
                W2t + ((nbase + nf) * 16 + ln) * D + kf * 32 + kq * 8);
            #pragma unroll
            for (int m = 0; m < 4; ++m)
                acc[m][nf] = __builtin_amdgcn_mfma_f32_16x16x32_bf16(a[m], b, acc[m][nf], 0, 0, 0);
        }
    }

    // epilogue
    float m = -INFINITY;
    #pragma unroll
    for (int mf = 0; mf < 4; ++mf)
        #pragma unroll
        for (int nf = 0; nf < NFW; ++nf)
            #pragma unroll
            for (int j = 0; j < 4; ++j) {
                int row = mf * 16 + kq * 4 + j;
                if (row < validRows) m = fmaxf(m, acc[mf][nf][j]);
            }
    #pragma unroll
    for (int off = 32; off; off >>= 1) m = fmaxf(m, __shfl_xor(m, off));
    if (l == 0) wmax[w] = m;
    __syncthreads();
    if (tid == 0)
        *bmslot = 0.125f * fmaxf(fmaxf(wmax[0], wmax[1]), fmaxf(wmax[2], wmax[3]));

    #pragma unroll
    for (int nf = 0; nf < NFW; ++nf) {
        const int c = (nbase + nf) * 16 + ln;
        const int slot = c >> 6;
        const int feat = c & 63;
        #pragma unroll
        for (int mf = 0; mf < 4; ++mf)
            #pragma unroll
            for (int j = 0; j < 4; ++j) {
                int row = mf * 16 + kq * 4 + j;
                float v = __expf(acc[mf][nf][j]);
                float nv = __shfl_xor(v, 1);
                if ((ln & 1) == 0 && row < validRows) {
                    int node = Ids[row * A + slot];
                    __half2 pk = __halves2half2(__float2half(v), __float2half(nv));
                    unsafeAtomicAdd(
                        reinterpret_cast<__half2*>(exps + (long long)node * 64 + feat), pk);
                }
            }
    }
}

// Arity-1 DEDUP body: block = 64 consecutive NODES (streaming gather, no idx);
// scatter cnt[n]*exp(8*o) once per unique node (exact vs cnt separate adds).
__device__ __forceinline__ void rel0_body(
    const u16* __restrict__ statesb, const int* __restrict__ cnt,
    const u16* __restrict__ W1t, const float* __restrict__ B1,
    const u16* __restrict__ W2t, const float* __restrict__ B2,
    __half* __restrict__ exps, float* __restrict__ bmslot, int Nn, int bid,
    u16* Xs, float* wmax) {
    constexpr int D = 64, KF = 2, CPR = 8;
    char* Xc = (char*)Xs;
    const int tid = threadIdx.x;
    const int block0 = bid * 64;
    const int validRows = min(64, Nn - block0);

    // streaming gather of nodes block0..block0+63 (swizzled chunks)
    for (int q = tid; q < 64 * CPR; q += 256) {
        int r = q / CPR, c = q - r * CPR;
        int wc = (c & 7) ^ (r & 7);
        bf16x8 v = {};
        if (r < validRows)
            v = *reinterpret_cast<const bf16x8*>(
                statesb + (long long)(block0 + r) * 64 + wc * 8);
        *reinterpret_cast<bf16x8*>(Xc + q * 16) = v;
    }
    __syncthreads();

    const int l = tid & 63;
    const int ln = l & 15, kq = l >> 4;
    const int w = tid >> 6;   // NFW=1: wave w owns n-frag w (cols w*16..)

    f32x4 acc[4];
    // layer 1
    {
        float b = B1[w * 16 + ln];
        #pragma unroll
        for (int m = 0; m < 4; ++m) acc[m] = {b, b, b, b};
    }
    #pragma unroll
    for (int kf = 0; kf < KF; ++kf) {
        bf16x8 a[4];
        #pragma unroll
        for (int m = 0; m < 4; ++m)
            a[m] = *reinterpret_cast<const bf16x8*>(
                Xc + (m * 16 + ln) * (2 * D) + ((kf * 64 + kq * 16) ^ ((ln & 7) << 4)));
        bf16x8 b = *reinterpret_cast<const bf16x8*>(
            W1t + (w * 16 + ln) * D + kf * 32 + kq * 8);
        #pragma unroll
        for (int m = 0; m < 4; ++m)
            acc[m] = __builtin_amdgcn_mfma_f32_16x16x32_bf16(a[m], b, acc[m], 0, 0, 0);
    }
    __syncthreads();
    #pragma unroll
    for (int m = 0; m < 4; ++m)
        #pragma unroll
        for (int j = 0; j < 4; ++j) {
            int row = m * 16 + kq * 4 + j;
            int byte = ((w * 16 + ln) * 2) ^ ((row & 7) << 4);
            *reinterpret_cast<u16*>(Xc + row * (2 * D) + byte) =
                f2bf(fmaxf(acc[m][j], 0.f));
        }
    __syncthreads();
    // layer 2 (pre-scaled by 8)
    {
        float b = 8.f * B2[w * 16 + ln];
        #pragma unroll
        for (int m = 0; m < 4; ++m) acc[m] = {b, b, b, b};
    }
    #pragma unroll
    for (int kf = 0; kf < KF; ++kf) {
        bf16x8 a[4];
        #pragma unroll
        for (int m = 0; m < 4; ++m)
            a[m] = *reinterpret_cast<const bf16x8*>(
                Xc + (m * 16 + ln) * (2 * D) + ((kf * 64 + kq * 16) ^ ((ln & 7) << 4)));
        bf16x8 b = *reinterpret_cast<const bf16x8*>(
            W2t + (w * 16 + ln) * D + kf * 32 + kq * 8);
        #pragma unroll
        for (int m = 0; m < 4; ++m)
            acc[m] = __builtin_amdgcn_mfma_f32_16x16x32_bf16(a[m], b, acc[m], 0, 0, 0);
    }

    // epilogue: max & scatter only where cnt>0
    float m = -INFINITY;
    int cn[4][4];
    #pragma unroll
    for (int mf = 0; mf < 4; ++mf)
        #pragma unroll
        for (int j = 0; j < 4; ++j) {
            int row = mf * 16 + kq * 4 + j;
            cn[mf][j] = (row < validRows) ? cnt[block0 + row] : 0;
            if (cn[mf][j] > 0) m = fmaxf(m, acc[mf][j]);
        }
    #pragma unroll
    for (int off = 32; off; off >>= 1) m = fmaxf(m, __shfl_xor(m, off));
    if (l == 0) wmax[w] = m;
    __syncthreads();
    if (tid == 0)
        *bmslot = 0.125f * fmaxf(fmaxf(wmax[0], wmax[1]), fmaxf(wmax[2], wmax[3]));

    const int feat = w * 16 + ln;
    #pragma unroll
    for (int mf = 0; mf < 4; ++mf)
        #pragma unroll
        for (int j = 0; j < 4; ++j) {
            int row = mf * 16 + kq * 4 + j;
            float cf = (float)cn[mf][j];
            float v = cf * __expf(acc[mf][j]);
            float nv = __shfl_xor(v, 1);
            if ((ln & 1) == 0 && cn[mf][j] > 0) {
                int node = block0 + row;
                __half2 pk = __halves2half2(__float2half(v), __float2half(nv));
                unsafeAtomicAdd(
                    reinterpret_cast<__half2*>(exps + (long long)node * 64 + feat), pk);
            }
        }
}

struct RelArgs {
    const u16* statesb;
    const int* cnt0; const int* idx1; const int* idx2;
    const u16* w1t0; const float* b10; const u16* w2t0; const float* b20;
    const u16* w1t1; const float* b11; const u16* w2t1; const float* b21;
    const u16* w1t2; const float* b12; const u16* w2t2; const float* b22;
    __half* exps;
    float* blockmax;
    int Nn, E1, E2, G0, G01;   // G01 = G0+G1
};

__global__ __launch_bounds__(256) void rel_fused(RelArgs a) {
    __shared__ __align__(16) u16 Xs[64 * 192];
    __shared__ int Ids[64 * 3];
    __shared__ float wmax[4];
    const int bid = blockIdx.x;
    if (bid < a.G0)
        rel0_body(a.statesb, a.cnt0, a.w1t0, a.b10, a.w2t0, a.b20,
                  a.exps, a.blockmax + bid, a.Nn, bid, Xs, wmax);
    else if (bid < a.G01)
        rel_body<128>(a.statesb, a.idx1, a.w1t1, a.b11, a.w2t1, a.b21,
                      a.exps, a.blockmax + bid, a.E1, bid - a.G0, Xs, Ids, wmax);
    else
        rel_body<192>(a.statesb, a.idx2, a.w1t2, a.b12, a.w2t2, a.b22,
                      a.exps, a.blockmax + bid, a.E2, bid - a.G01, Xs, Ids, wmax);
}

// ---------------- global max over block maxima ----------------
__global__ __launch_bounds__(256) void reduce_max(const float* __restrict__ bm,
                                                  int n, float* __restrict__ out) {
    __shared__ float ws_[4];
    float m = -INFINITY;
    for (int i = threadIdx.x; i < n; i += 256) m = fmaxf(m, bm[i]);
    #pragma unroll
    for (int off = 32; off; off >>= 1) m = fmaxf(m, __shfl_xor(m, off));
    if ((threadIdx.x & 63) == 0) ws_[threadIdx.x >> 6] = m;
    __syncthreads();
    if (threadIdx.x == 0)
        out[0] = fmaxf(fmaxf(ws_[0], ws_[1]), fmaxf(ws_[2], ws_[3]));
}

// ---------------- up kernel ----------------
__global__ __launch_bounds__(256) void up_mfma(
    const u16* __restrict__ statesb, const _Float16* __restrict__ exps,
    const float* __restrict__ gmaxp,
    const u16* __restrict__ W1t, const float* __restrict__ B1,
    const u16* __restrict__ W2t, const float* __restrict__ B2,
    float* __restrict__ outp, int Nn) {
    constexpr int D = 128;
    __shared__ __align__(16) u16 Xs[64 * D];
    char* Xc = (char*)Xs;
    const int tid = threadIdx.x;
    const int block0 = blockIdx.x * 64;
    const int validRows = min(64, Nn - block0);
    const float M = gmaxp[0];
    const float EM = __expf(-8.f * M);

    for (int q = tid; q < 64 * 16; q += 256) {
        int r = q >> 4, p = q & 15;
        bf16x8 v = {};
        if (r < validRows) {
            long long nd = block0 + r;
            if (p < 8) {
                f16x8 s = *reinterpret_cast<const f16x8*>(exps + nd * 64 + p * 8);
                #pragma unroll
                for (int i = 0; i < 8; ++i)
                    v[i] = (short)f2bf(__logf(1e-16f + (float)s[i] * EM) * 0.125f + M);
            } else {
                v = *reinterpret_cast<const bf16x8*>(statesb + nd * 64 + (p - 8) * 8);
            }
        }
        int byte = (p * 16) ^ ((r & 7) << 4);
        *reinterpret_cast<bf16x8*>(Xc + r * 256 + byte) = v;
    }
    __syncthreads();

    const int l = tid & 63;
    const int ln = l & 15, kq = l >> 4;
    const int row0 = (tid >> 6) * 16;

    f32x4 acc[8];
    #pragma unroll
    for (int n = 0; n < 8; ++n) {
        float b = B1[n * 16 + ln];
        acc[n] = {b, b, b, b};
    }
    {
        const u16* wb = W1t + ln * D + kq * 8;
        #pragma unroll
        for (int kf = 0; kf < 4; ++kf) {
            bf16x8 a = *reinterpret_cast<const bf16x8*>(
                Xc + (row0 + ln) * 256 + ((kf * 64 + kq * 16) ^ ((ln & 7) << 4)));
            #pragma unroll
            for (int n = 0; n < 8; ++n) {
                bf16x8 b = *reinterpret_cast<const bf16x8*>(wb + n * 16 * D + kf * 32);
                acc[n] = __builtin_amdgcn_mfma_f32_16x16x32_bf16(a, b, acc[n], 0, 0, 0);
            }
        }
    }
    #pragma unroll
    for (int n = 0; n < 8; ++n) {
        #pragma unroll
        for (int j = 0; j < 4; ++j) {
            int rl = kq * 4 + j;
            int byte = ((n * 16 + ln) * 2) ^ ((rl & 7) << 4);
            *reinterpret_cast<u16*>(Xc + (row0 + rl) * 256 + byte) =
                f2bf(fmaxf(acc[n][j], 0.f));
        }
    }
    f32x4 acc2[4];
    #pragma unroll
    for (int n = 0; n < 4; ++n) {
        float b = B2[n * 16 + ln];
        acc2[n] = {b, b, b, b};
    }
    {
        const u16* wb = W2t + ln * D + kq * 8;   // W2t is [64][128]
        #pragma unroll
        for (int kf = 0; kf < 4; ++kf) {
            bf16x8 a = *reinterpret_cast<const bf16x8*>(
                Xc + (row0 + ln) * 256 + ((kf * 64 + kq * 16) ^ ((ln & 7) << 4)));
            #pragma unroll
            for (int n = 0; n < 4; ++n) {
                bf16x8 b = *reinterpret_cast<const bf16x8*>(wb + n * 16 * D + kf * 32);
                acc2[n] = __builtin_amdgcn_mfma_f32_16x16x32_bf16(a, b, acc2[n], 0, 0, 0);
            }
        }
    }
    #pragma unroll
    for (int n = 0; n < 4; ++n)
        #pragma unroll
        for (int j = 0; j < 4; ++j) {
            int row = row0 + kq * 4 + j;
            if (row < validRows)
                outp[(long long)(block0 + row) * 64 + n * 16 + ln] = acc2[n][j];
        }
}

extern "C" void kernel_launch(void* const* d_in, const int* in_sizes, int n_in,
                              void* d_out, int out_size, void* d_ws, size_t ws_size,
                              hipStream_t stream) {
    const float* states = (const float*)d_in[0];
    const int* idxp[3] = {(const int*)d_in[1], (const int*)d_in[2], (const int*)d_in[3]};
    const float* rw1[3] = {(const float*)d_in[4], (const float*)d_in[8], (const float*)d_in[12]};
    const float* rb1[3] = {(const float*)d_in[5], (const float*)d_in[9], (const float*)d_in[13]};
    const float* rw2[3] = {(const float*)d_in[6], (const float*)d_in[10], (const float*)d_in[14]};
    const float* rb2[3] = {(const float*)d_in[7], (const float*)d_in[11], (const float*)d_in[15]};
    const float* upw1 = (const float*)d_in[16];
    const float* upb1 = (const float*)d_in[17];
    const float* upw2 = (const float*)d_in[18];
    const float* upb2 = (const float*)d_in[19];

    const int N = in_sizes[0] / 64;
    const int L0 = in_sizes[1];
    const int E1 = in_sizes[2] / 2;
    const int E2 = in_sizes[3] / 3;
    const int G0 = (N + 63) / 64;            // dedup: blocks over NODES
    const int G1 = (E1 + 63) / 64, G2 = (E2 + 63) / 64;
    const int Gtot = G0 + G1 + G2;
    const int Dd[3] = {64, 128, 192};

    size_t off = 0;
    auto alloc = [&](size_t bytes) {
        void* p = (char*)d_ws + off;
        off += (bytes + 255) & ~(size_t)255;
        return p;
    };
    float* gmaxf = (float*)alloc(4);
    float* blockmax = (float*)alloc((size_t)Gtot * 4);
    __half* exps = (__half*)alloc((size_t)N * 64 * 2);
    int* hist0 = (int*)alloc((size_t)N * 4);          // adjacent to exps
    size_t zlen = (size_t)((char*)hist0 - (char*)exps) + (size_t)N * 4;
    u16* statesb = (u16*)alloc((size_t)N * 64 * 2);
    u16* w1t[3], *w2t[3];
    for (int r = 0; r < 3; ++r) {
        w1t[r] = (u16*)alloc((size_t)Dd[r] * Dd[r] * 2);
        w2t[r] = (u16*)alloc((size_t)Dd[r] * Dd[r] * 2);
    }
    u16* upw1t = (u16*)alloc(128 * 128 * 2);
    u16* upw2t = (u16*)alloc(64 * 128 * 2);

    // zero exps + hist0 (one contiguous region)
    (void)hipMemsetAsync(exps, 0, zlen, stream);

    conv_states<<<dim3((N * 64 / 8 + 255) / 256), dim3(256), 0, stream>>>(
        states, statesb, N * 64 / 8);

    TPack tp;
    const float* tsrc[8] = {rw1[0], rw2[0], rw1[1], rw2[1], rw1[2], rw2[2], upw1, upw2};
    u16* tdst[8] = {w1t[0], w2t[0], w1t[1], w2t[1], w1t[2], w2t[2], upw1t, upw2t};
    const int tK[8] = {64, 64, 128, 128, 192, 192, 128, 128};
    const int tN[8] = {64, 64, 128, 128, 192, 192, 128, 64};
    const float tsc[8] = {1.f, 8.f, 1.f, 8.f, 1.f, 8.f, 1.f, 1.f};
    int base = 0;
    for (int i = 0; i < 8; ++i) {
        tp.e[i] = {tsrc[i], tdst[i], tK[i], tN[i], base, tsc[i]};
        base += (tK[i] * tN[i] + 255) / 256;
    }
    transpose_w<<<dim3(base), dim3(256), 0, stream>>>(tp);

    hist_k<<<dim3((L0 + 255) / 256), dim3(256), 0, stream>>>(idxp[0], L0, hist0);

    RelArgs ra;
    ra.statesb = statesb;
    ra.cnt0 = hist0; ra.idx1 = idxp[1]; ra.idx2 = idxp[2];
    ra.w1t0 = w1t[0]; ra.b10 = rb1[0]; ra.w2t0 = w2t[0]; ra.b20 = rb2[0];
    ra.w1t1 = w1t[1]; ra.b11 = rb1[1]; ra.w2t1 = w2t[1]; ra.b21 = rb2[1];
    ra.w1t2 = w1t[2]; ra.b12 = rb1[2]; ra.w2t2 = w2t[2]; ra.b22 = rb2[2];
    ra.exps = exps;
    ra.blockmax = blockmax;
    ra.Nn = N; ra.E1 = E1; ra.E2 = E2; ra.G0 = G0; ra.G01 = G0 + G1;

    rel_fused<<<dim3(Gtot), dim3(256), 0, stream>>>(ra);

    reduce_max<<<dim3(1), dim3(256), 0, stream>>>(blockmax, Gtot, gmaxf);

    up_mfma<<<dim3((N + 63) / 64), dim3(256), 0, stream>>>(
        statesb, (const _Float16*)exps, gmaxf, upw1t, upb1, upw2t, upb2,
        (float*)d_out, N);
}

// Round 16
// 345.104 us; speedup vs baseline: 2.1495x; 1.2759x over previous
//
#include <hip/hip_runtime.h>
#include <hip/hip_fp16.h>
#include <math.h>

// RelationMessagePassing — bf16 MFMA, fused rel kernel (deduped arity-1),
// LDS-staged FULL-WAVE-COALESCED packed-fp16 atomic scatter.
// (Resubmit: round-15 infra failure, kernel untested.)
//
// Round-14: byte model confirmed (WRITE == atomic payload == 188 MB, time ==
// bytes/~750GB/s). Atomic payload is already minimal; this round targets the
// RATE: old epilogue scattered 32 even-lanes over 4 nodes x 32B per issue
// (partial-line RMW groups + shfl/predication). New epilogue stages exp(acc)
// fp16 into LDS [seg][feat] (A*8KB, fits Xs), then scatters with 64 lanes
// covering 2 segs x 128B contiguous -> line-aligned RMWs, half the issues.
//
// Pipeline: memset(exps+hist0) | conv_states | transpose_w (W2 pre-scaled 8) |
//   hist_k(idx0) | rel_fused: [r0-dedup | rel<128> | rel<192>] ->
//     blockmax[bid] + staged pk_f16 atomics | reduce_max | up_mfma -> fp32.

typedef __attribute__((ext_vector_type(8))) short bf16x8;
typedef __attribute__((ext_vector_type(4))) float f32x4;
typedef __attribute__((ext_vector_type(8))) _Float16 f16x8;
typedef unsigned short u16;

__device__ __forceinline__ u16 f2bf(float f) {   // RNE f32->bf16 (finite)
    unsigned u = __float_as_uint(f);
    return (u16)((u + 0x7fffu + ((u >> 16) & 1u)) >> 16);
}

// ---------------- prep ----------------
__global__ __launch_bounds__(256) void conv_states(const float* __restrict__ src,
                                                   u16* __restrict__ dst, int n8) {
    int i = blockIdx.x * 256 + threadIdx.x;
    if (i >= n8) return;
    float4 a = reinterpret_cast<const float4*>(src)[2 * i];
    float4 b = reinterpret_cast<const float4*>(src)[2 * i + 1];
    bf16x8 v;
    v[0] = (short)f2bf(a.x); v[1] = (short)f2bf(a.y);
    v[2] = (short)f2bf(a.z); v[3] = (short)f2bf(a.w);
    v[4] = (short)f2bf(b.x); v[5] = (short)f2bf(b.y);
    v[6] = (short)f2bf(b.z); v[7] = (short)f2bf(b.w);
    reinterpret_cast<bf16x8*>(dst)[i] = v;
}

struct TEnt { const float* src; u16* dst; int K, N, base; float scale; };
struct TPack { TEnt e[8]; };
// dst[n*K + k] = bf16(scale * src[k*N + n])
__global__ __launch_bounds__(256) void transpose_w(TPack p) {
    int b = blockIdx.x;
    int i = 0;
    while (i < 7 && b >= p.e[i + 1].base) ++i;
    TEnt e = p.e[i];
    int idx = (b - e.base) * 256 + threadIdx.x;
    if (idx < e.K * e.N) {
        int n = idx / e.K, k = idx - n * e.K;
        e.dst[idx] = f2bf(e.scale * e.src[k * e.N + n]);
    }
}

__global__ __launch_bounds__(256) void hist_k(const int* __restrict__ idx, int n,
                                              int* __restrict__ hist) {
    int i = blockIdx.x * 256 + threadIdx.x;
    if (i < n) atomicAdd(&hist[idx[i]], 1);
}

// ---------------- relation bodies ----------------
// Generic (arity 2/3): block = 64 tuples, 4 waves; wave w owns cols
// [w*D/4,(w+1)*D/4) x all 64 rows. Layer2 pre-scaled by 8 => acc' = 8*o.
template <int D>
__device__ __forceinline__ void rel_body(
    const u16* __restrict__ statesb, const int* __restrict__ idx,
    const u16* __restrict__ W1t, const float* __restrict__ B1,
    const u16* __restrict__ W2t, const float* __restrict__ B2,
    __half* __restrict__ exps, float* __restrict__ bmslot, int E, int bid,
    u16* Xs, int* Ids, float* wmax) {
    constexpr int A = D / 64;
    constexpr int KF = D / 32;
    constexpr int NFW = D / 64;
    constexpr int CPR = D / 8;
    char* Xc = (char*)Xs;

    const int tid = threadIdx.x;
    const int block0 = bid * 64;
    const int validRows = min(64, E - block0);
    const int validSegs = validRows * A;
    const long long segBase = (long long)block0 * A;

    // gather: LDS(r,c) holds global chunk (c&7)^(r&7) of node[c>>3]
    for (int q = tid; q < 64 * CPR; q += 256) {
        int r = q / CPR, c = q - r * CPR;
        int slot = c >> 3;
        int wc = (c & 7) ^ (r & 7);
        int seg = r * A + slot;
        bf16x8 v = {};
        if (seg < validSegs) {
            int node = idx[segBase + seg];
            v = *reinterpret_cast<const bf16x8*>(statesb + (long long)node * 64 + wc * 8);
            if ((c & 7) == 0) Ids[seg] = node;
        }
        *reinterpret_cast<bf16x8*>(Xc + q * 16) = v;
    }
    __syncthreads();

    const int l = tid & 63;
    const int ln = l & 15, kq = l >> 4;
    const int w = tid >> 6;
    const int nbase = w * NFW;

    f32x4 acc[4][NFW];

    // layer 1
    #pragma unroll
    for (int nf = 0; nf < NFW; ++nf) {
        float b = B1[(nbase + nf) * 16 + ln];
        #pragma unroll
        for (int m = 0; m < 4; ++m) acc[m][nf] = {b, b, b, b};
    }
    #pragma unroll
    for (int kf = 0; kf < KF; ++kf) {
        bf16x8 a[4];
        #pragma unroll
        for (int m = 0; m < 4; ++m)
            a[m] = *reinterpret_cast<const bf16x8*>(
                Xc + (m * 16 + ln) * (2 * D) + ((kf * 64 + kq * 16) ^ ((ln & 7) << 4)));
        #pragma unroll
        for (int nf = 0; nf < NFW; ++nf) {
            bf16x8 b = *reinterpret_cast<const bf16x8*>(
                W1t + ((nbase + nf) * 16 + ln) * D + kf * 32 + kq * 8);
            #pragma unroll
            for (int m = 0; m < 4; ++m)
                acc[m][nf] = __builtin_amdgcn_mfma_f32_16x16x32_bf16(a[m], b, acc[m][nf], 0, 0, 0);
        }
    }
    __syncthreads();
    // relu -> H
    #pragma unroll
    for (int nf = 0; nf < NFW; ++nf) {
        const int c = (nbase + nf) * 16 + ln;
        #pragma unroll
        for (int m = 0; m < 4; ++m)
            #pragma unroll
            for (int j = 0; j < 4; ++j) {
                int row = m * 16 + kq * 4 + j;
                int byte = (c * 2) ^ ((row & 7) << 4);
                *reinterpret_cast<u16*>(Xc + row * (2 * D) + byte) =
                    f2bf(fmaxf(acc[m][nf][j], 0.f));
            }
    }
    __syncthreads();

    // layer 2 (pre-scaled by 8)
    #pragma unroll
    for (int nf = 0; nf < NFW; ++nf) {
        float b = 8.f * B2[(nbase + nf) * 16 + ln];
        #pragma unroll
        for (int m = 0; m < 4; ++m) acc[m][nf] = {b, b, b, b};
    }
    #pragma unroll
    for (int kf = 0; kf < KF; ++kf) {
        bf16x8 a[4];
        #pragma unroll
        for (int m = 0; m < 4; ++m)
            a[m] = *reinterpret_cast<const bf16x8*>(
                Xc + (m * 16 + ln) * (2 * D) + ((kf * 64 + kq * 16) ^ ((ln & 7) << 4)));
        #pragma unroll
        for (int nf = 0; nf < NFW; ++nf) {
            bf16x8 b = *reinterpret_cast<const bf16x8*>(
                W2t + ((nbase + nf) * 16 + ln) * D + kf * 32 + kq * 8);
            #pragma unroll
            for (int m = 0; m < 4; ++m)
                acc[m][nf] = __builtin_amdgcn_mfma_f32_16x16x32_bf16(a[m], b, acc[m][nf], 0, 0, 0);
        }
    }

    // ---- epilogue: block max; stage exp(acc') fp16 in LDS [seg][feat];
    //      full-wave coalesced pk atomics (2 segs x 128B per issue).
    float m = -INFINITY;
    #pragma unroll
    for (int mf = 0; mf < 4; ++mf)
        #pragma unroll
        for (int nf = 0; nf < NFW; ++nf)
            #pragma unroll
            for (int j = 0; j < 4; ++j) {
                int row = mf * 16 + kq * 4 + j;
                if (row < validRows) m = fmaxf(m, acc[mf][nf][j]);
            }
    #pragma unroll
    for (int off = 32; off; off >>= 1) m = fmaxf(m, __shfl_xor(m, off));
    if (l == 0) wmax[w] = m;
    __syncthreads();   // also guarantees all layer-2 LDS reads complete
    if (tid == 0)
        *bmslot = 0.125f * fmaxf(fmaxf(wmax[0], wmax[1]), fmaxf(wmax[2], wmax[3]));

    _Float16* Xh = (_Float16*)Xc;
    #pragma unroll
    for (int nf = 0; nf < NFW; ++nf) {
        const int c = (nbase + nf) * 16 + ln;
        const int slot = c >> 6;
        const int feat = c & 63;
        #pragma unroll
        for (int mf = 0; mf < 4; ++mf)
            #pragma unroll
            for (int j = 0; j < 4; ++j) {
                int row = mf * 16 + kq * 4 + j;
                Xh[(row * A + slot) * 64 + feat] = (_Float16)__expf(acc[mf][nf][j]);
            }
    }
    __syncthreads();

    {
        constexpr int SPW = 16 * A;          // segs per wave
        const int fp = l & 31;               // feat-pair index
        for (int s0 = w * SPW; s0 < (w + 1) * SPW; s0 += 2) {
            int seg = s0 + (l >> 5);
            if (seg < validSegs) {
                int node = Ids[seg];
                __half2 pk = *reinterpret_cast<const __half2*>(Xc + seg * 128 + fp * 4);
                unsafeAtomicAdd(reinterpret_cast<__half2*>(
                    exps + (long long)node * 64 + fp * 2), pk);
            }
        }
    }
}

// Arity-1 DEDUP body: block = 64 consecutive NODES (streaming gather, no idx);
// scatter cnt[n]*exp(8*o) once per unique node (exact vs cnt separate adds).
__device__ __forceinline__ void rel0_body(
    const u16* __restrict__ statesb, const int* __restrict__ cnt,
    const u16* __restrict__ W1t, const float* __restrict__ B1,
    const u16* __restrict__ W2t, const float* __restrict__ B2,
    __half* __restrict__ exps, float* __restrict__ bmslot, int Nn, int bid,
    u16* Xs, float* wmax) {
    constexpr int D = 64, KF = 2, CPR = 8;
    char* Xc = (char*)Xs;
    const int tid = threadIdx.x;
    const int block0 = bid * 64;
    const int validRows = min(64, Nn - block0);

    // streaming gather of nodes block0..block0+63 (swizzled chunks)
    for (int q = tid; q < 64 * CPR; q += 256) {
        int r = q / CPR, c = q - r * CPR;
        int wc = (c & 7) ^ (r & 7);
        bf16x8 v = {};
        if (r < validRows)
            v = *reinterpret_cast<const bf16x8*>(
                statesb + (long long)(block0 + r) * 64 + wc * 8);
        *reinterpret_cast<bf16x8*>(Xc + q * 16) = v;
    }
    __syncthreads();

    const int l = tid & 63;
    const int ln = l & 15, kq = l >> 4;
    const int w = tid >> 6;   // NFW=1: wave w owns n-frag w (cols w*16..)

    f32x4 acc[4];
    // layer 1
    {
        float b = B1[w * 16 + ln];
        #pragma unroll
        for (int m = 0; m < 4; ++m) acc[m] = {b, b, b, b};
    }
    #pragma unroll
    for (int kf = 0; kf < KF; ++kf) {
        bf16x8 a[4];
        #pragma unroll
        for (int m = 0; m < 4; ++m)
            a[m] = *reinterpret_cast<const bf16x8*>(
                Xc + (m * 16 + ln) * (2 * D) + ((kf * 64 + kq * 16) ^ ((ln & 7) << 4)));
        bf16x8 b = *reinterpret_cast<const bf16x8*>(
            W1t + (w * 16 + ln) * D + kf * 32 + kq * 8);
        #pragma unroll
        for (int m = 0; m < 4; ++m)
            acc[m] = __builtin_amdgcn_mfma_f32_16x16x32_bf16(a[m], b, acc[m], 0, 0, 0);
    }
    __syncthreads();
    #pragma unroll
    for (int m = 0; m < 4; ++m)
        #pragma unroll
        for (int j = 0; j < 4; ++j) {
            int row = m * 16 + kq * 4 + j;
            int byte = ((w * 16 + ln) * 2) ^ ((row & 7) << 4);
            *reinterpret_cast<u16*>(Xc + row * (2 * D) + byte) =
                f2bf(fmaxf(acc[m][j], 0.f));
        }
    __syncthreads();
    // layer 2 (pre-scaled by 8)
    {
        float b = 8.f * B2[w * 16 + ln];
        #pragma unroll
        for (int m = 0; m < 4; ++m) acc[m] = {b, b, b, b};
    }
    #pragma unroll
    for (int kf = 0; kf < KF; ++kf) {
        bf16x8 a[4];
        #pragma unroll
        for (int m = 0; m < 4; ++m)
            a[m] = *reinterpret_cast<const bf16x8*>(
                Xc + (m * 16 + ln) * (2 * D) + ((kf * 64 + kq * 16) ^ ((ln & 7) << 4)));
        bf16x8 b = *reinterpret_cast<const bf16x8*>(
            W2t + (w * 16 + ln) * D + kf * 32 + kq * 8);
        #pragma unroll
        for (int m = 0; m < 4; ++m)
            acc[m] = __builtin_amdgcn_mfma_f32_16x16x32_bf16(a[m], b, acc[m], 0, 0, 0);
    }

    // epilogue: max over cnt>0; stage cnt*exp fp16; full-wave coalesced scatter
    float m = -INFINITY;
    int cn[4][4];
    #pragma unroll
    for (int mf = 0; mf < 4; ++mf)
        #pragma unroll
        for (int j = 0; j < 4; ++j) {
            int row = mf * 16 + kq * 4 + j;
            cn[mf][j] = (row < validRows) ? cnt[block0 + row] : 0;
            if (cn[mf][j] > 0) m = fmaxf(m, acc[mf][j]);
        }
    #pragma unroll
    for (int off = 32; off; off >>= 1) m = fmaxf(m, __shfl_xor(m, off));
    if (l == 0) wmax[w] = m;
    __syncthreads();   // layer-2 LDS reads complete
    if (tid == 0)
        *bmslot = 0.125f * fmaxf(fmaxf(wmax[0], wmax[1]), fmaxf(wmax[2], wmax[3]));

    _Float16* Xh = (_Float16*)Xc;
    const int feat = w * 16 + ln;
    #pragma unroll
    for (int mf = 0; mf < 4; ++mf)
        #pragma unroll
        for (int j = 0; j < 4; ++j) {
            int row = mf * 16 + kq * 4 + j;
            Xh[row * 64 + feat] = (_Float16)((float)cn[mf][j] * __expf(acc[mf][j]));
        }
    __syncthreads();

    {
        const int fp = l & 31;
        for (int s0 = w * 16; s0 < (w + 1) * 16; s0 += 2) {
            int row = s0 + (l >> 5);
            if (row < validRows && cnt[block0 + row] > 0) {
                __half2 pk = *reinterpret_cast<const __half2*>(Xc + row * 128 + fp * 4);
                unsafeAtomicAdd(reinterpret_cast<__half2*>(
                    exps + (long long)(block0 + row) * 64 + fp * 2), pk);
            }
        }
    }
}

struct RelArgs {
    const u16* statesb;
    const int* cnt0; const int* idx1; const int* idx2;
    const u16* w1t0; const float* b10; const u16* w2t0; const float* b20;
    const u16* w1t1; const float* b11; const u16* w2t1; const float* b21;
    const u16* w1t2; const float* b12; const u16* w2t2; const float* b22;
    __half* exps;
    float* blockmax;
    int Nn, E1, E2, G0, G01;   // G01 = G0+G1
};

__global__ __launch_bounds__(256) void rel_fused(RelArgs a) {
    __shared__ __align__(16) u16 Xs[64 * 192];
    __shared__ int Ids[64 * 3];
    __shared__ float wmax[4];
    const int bid = blockIdx.x;
    if (bid < a.G0)
        rel0_body(a.statesb, a.cnt0, a.w1t0, a.b10, a.w2t0, a.b20,
                  a.exps, a.blockmax + bid, a.Nn, bid, Xs, wmax);
    else if (bid < a.G01)
        rel_body<128>(a.statesb, a.idx1, a.w1t1, a.b11, a.w2t1, a.b21,
                      a.exps, a.blockmax + bid, a.E1, bid - a.G0, Xs, Ids, wmax);
    else
        rel_body<192>(a.statesb, a.idx2, a.w1t2, a.b12, a.w2t2, a.b22,
                      a.exps, a.blockmax + bid, a.E2, bid - a.G01, Xs, Ids, wmax);
}

// ---------------- global max over block maxima ----------------
__global__ __launch_bounds__(256) void reduce_max(const float* __restrict__ bm,
                                                  int n, float* __restrict__ out) {
    __shared__ float ws_[4];
    float m = -INFINITY;
    for (int i = threadIdx.x; i < n; i += 256) m = fmaxf(m, bm[i]);
    #pragma unroll
    for (int off = 32; off; off >>= 1) m = fmaxf(m, __shfl_xor(m, off));
    if ((threadIdx.x & 63) == 0) ws_[threadIdx.x >> 6] = m;
    __syncthreads();
    if (threadIdx.x == 0)
        out[0] = fmaxf(fmaxf(ws_[0], ws_[1]), fmaxf(ws_[2], ws_[3]));
}

// ---------------- up kernel ----------------
__global__ __launch_bounds__(256) void up_mfma(
    const u16* __restrict__ statesb, const _Float16* __restrict__ exps,
    const float* __restrict__ gmaxp,
    const u16* __restrict__ W1t, const float* __restrict__ B1,
    const u16* __restrict__ W2t, const float* __restrict__ B2,
    float* __restrict__ outp, int Nn) {
    constexpr int D = 128;
    __shared__ __align__(16) u16 Xs[64 * D];
    char* Xc = (char*)Xs;
    const int tid = threadIdx.x;
    const int block0 = blockIdx.x * 64;
    const int validRows = min(64, Nn - block0);
    const float M = gmaxp[0];
    const float EM = __expf(-8.f * M);

    for (int q = tid; q < 64 * 16; q += 256) {
        int r = q >> 4, p = q & 15;
        bf16x8 v = {};
        if (r < validRows) {
            long long nd = block0 + r;
            if (p < 8) {
                f16x8 s = *reinterpret_cast<const f16x8*>(exps + nd * 64 + p * 8);
                #pragma unroll
                for (int i = 0; i < 8; ++i)
                    v[i] = (short)f2bf(__logf(1e-16f + (float)s[i] * EM) * 0.125f + M);
            } else {
                v = *reinterpret_cast<const bf16x8*>(statesb + nd * 64 + (p - 8) * 8);
            }
        }
        int byte = (p * 16) ^ ((r & 7) << 4);
        *reinterpret_cast<bf16x8*>(Xc + r * 256 + byte) = v;
    }
    __syncthreads();

    const int l = tid & 63;
    const int ln = l & 15, kq = l >> 4;
    const int row0 = (tid >> 6) * 16;

    f32x4 acc[8];
    #pragma unroll
    for (int n = 0; n < 8; ++n) {
        float b = B1[n * 16 + ln];
        acc[n] = {b, b, b, b};
    }
    {
        const u16* wb = W1t + ln * D + kq * 8;
        #pragma unroll
        for (int kf = 0; kf < 4; ++kf) {
            bf16x8 a = *reinterpret_cast<const bf16x8*>(
                Xc + (row0 + ln) * 256 + ((kf * 64 + kq * 16) ^ ((ln & 7) << 4)));
            #pragma unroll
            for (int n = 0; n < 8; ++n) {
                bf16x8 b = *reinterpret_cast<const bf16x8*>(wb + n * 16 * D + kf * 32);
                acc[n] = __builtin_amdgcn_mfma_f32_16x16x32_bf16(a, b, acc[n], 0, 0, 0);
            }
        }
    }
    #pragma unroll
    for (int n = 0; n < 8; ++n) {
        #pragma unroll
        for (int j = 0; j < 4; ++j) {
            int rl = kq * 4 + j;
            int byte = ((n * 16 + ln) * 2) ^ ((rl & 7) << 4);
            *reinterpret_cast<u16*>(Xc + (row0 + rl) * 256 + byte) =
                f2bf(fmaxf(acc[n][j], 0.f));
        }
    }
    f32x4 acc2[4];
    #pragma unroll
    for (int n = 0; n < 4; ++n) {
        float b = B2[n * 16 + ln];
        acc2[n] = {b, b, b, b};
    }
    {
        const u16* wb = W2t + ln * D + kq * 8;   // W2t is [64][128]
        #pragma unroll
        for (int kf = 0; kf < 4; ++kf) {
            bf16x8 a = *reinterpret_cast<const bf16x8*>(
                Xc + (row0 + ln) * 256 + ((kf * 64 + kq * 16) ^ ((ln & 7) << 4)));
            #pragma unroll
            for (int n = 0; n < 4; ++n) {
                bf16x8 b = *reinterpret_cast<const bf16x8*>(wb + n * 16 * D + kf * 32);
                acc2[n] = __builtin_amdgcn_mfma_f32_16x16x32_bf16(a, b, acc2[n], 0, 0, 0);
            }
        }
    }
    #pragma unroll
    for (int n = 0; n < 4; ++n)
        #pragma unroll
        for (int j = 0; j < 4; ++j) {
            int row = row0 + kq * 4 + j;
            if (row < validRows)
                outp[(long long)(block0 + row) * 64 + n * 16 + ln] = acc2[n][j];
        }
}

extern "C" void kernel_launch(void* const* d_in, const int* in_sizes, int n_in,
                              void* d_out, int out_size, void* d_ws, size_t ws_size,
                              hipStream_t stream) {
    const float* states = (const float*)d_in[0];
    const int* idxp[3] = {(const int*)d_in[1], (const int*)d_in[2], (const int*)d_in[3]};
    const float* rw1[3] = {(const float*)d_in[4], (const float*)d_in[8], (const float*)d_in[12]};
    const float* rb1[3] = {(const float*)d_in[5], (const float*)d_in[9], (const float*)d_in[13]};
    const float* rw2[3] = {(const float*)d_in[6], (const float*)d_in[10], (const float*)d_in[14]};
    const float* rb2[3] = {(const float*)d_in[7], (const float*)d_in[11], (const float*)d_in[15]};
    const float* upw1 = (const float*)d_in[16];
    const float* upb1 = (const float*)d_in[17];
    const float* upw2 = (const float*)d_in[18];
    const float* upb2 = (const float*)d_in[19];

    const int N = in_sizes[0] / 64;
    const int L0 = in_sizes[1];
    const int E1 = in_sizes[2] / 2;
    const int E2 = in_sizes[3] / 3;
    const int G0 = (N + 63) / 64;            // dedup: blocks over NODES
    const int G1 = (E1 + 63) / 64, G2 = (E2 + 63) / 64;
    const int Gtot = G0 + G1 + G2;
    const int Dd[3] = {64, 128, 192};

    size_t off = 0;
    auto alloc = [&](size_t bytes) {
        void* p = (char*)d_ws + off;
        off += (bytes + 255) & ~(size_t)255;
        return p;
    };
    float* gmaxf = (float*)alloc(4);
    float* blockmax = (float*)alloc((size_t)Gtot * 4);
    __half* exps = (__half*)alloc((size_t)N * 64 * 2);
    int* hist0 = (int*)alloc((size_t)N * 4);          // adjacent to exps
    size_t zlen = (size_t)((char*)hist0 - (char*)exps) + (size_t)N * 4;
    u16* statesb = (u16*)alloc((size_t)N * 64 * 2);
    u16* w1t[3], *w2t[3];
    for (int r = 0; r < 3; ++r) {
        w1t[r] = (u16*)alloc((size_t)Dd[r] * Dd[r] * 2);
        w2t[r] = (u16*)alloc((size_t)Dd[r] * Dd[r] * 2);
    }
    u16* upw1t = (u16*)alloc(128 * 128 * 2);
    u16* upw2t = (u16*)alloc(64 * 128 * 2);

    // zero exps + hist0 (one contiguous region)
    (void)hipMemsetAsync(exps, 0, zlen, stream);

    conv_states<<<dim3((N * 64 / 8 + 255) / 256), dim3(256), 0, stream>>>(
        states, statesb, N * 64 / 8);

    TPack tp;
    const float* tsrc[8] = {rw1[0], rw2[0], rw1[1], rw2[1], rw1[2], rw2[2], upw1, upw2};
    u16* tdst[8] = {w1t[0], w2t[0], w1t[1], w2t[1], w1t[2], w2t[2], upw1t, upw2t};
    const int tK[8] = {64, 64, 128, 128, 192, 192, 128, 128};
    const int tN[8] = {64, 64, 128, 128, 192, 192, 128, 64};
    const float tsc[8] = {1.f, 8.f, 1.f, 8.f, 1.f, 8.f, 1.f, 1.f};
    int base = 0;
    for (int i = 0; i < 8; ++i) {
        tp.e[i] = {tsrc[i], tdst[i], tK[i], tN[i], base, tsc[i]};
        base += (tK[i] * tN[i] + 255) / 256;
    }
    transpose_w<<<dim3(base), dim3(256), 0, stream>>>(tp);

    hist_k<<<dim3((L0 + 255) / 256), dim3(256), 0, stream>>>(idxp[0], L0, hist0);

    RelArgs ra;
    ra.statesb = statesb;
    ra.cnt0 = hist0; ra.idx1 = idxp[1]; ra.idx2 = idxp[2];
    ra.w1t0 = w1t[0]; ra.b10 = rb1[0]; ra.w2t0 = w2t[0]; ra.b20 = rb2[0];
    ra.w1t1 = w1t[1]; ra.b11 = rb1[1]; ra.w2t1 = w2t[1]; ra.b21 = rb2[1];
    ra.w1t2 = w1t[2]; ra.b12 = rb1[2]; ra.w2t2 = w2t[2]; ra.b22 = rb2[2];
    ra.exps = exps;
    ra.blockmax = blockmax;
    ra.Nn = N; ra.E1 = E1; ra.E2 = E2; ra.G0 = G0; ra.G01 = G0 + G1;

    rel_fused<<<dim3(Gtot), dim3(256), 0, stream>>>(ra);

    reduce_max<<<dim3(1), dim3(256), 0, stream>>>(blockmax, Gtot, gmaxf);

    up_mfma<<<dim3((N + 63) / 64), dim3(256), 0, stream>>>(
        statesb, (const _Float16*)exps, gmaxf, upw1t, upb1, upw2t, upb2,
        (float*)d_out, N);
}